// Round 2
// baseline (1316.637 us; speedup 1.0000x reference)
//
#include <hip/hip_runtime.h>
#include <hip/hip_bf16.h>
#include <cstdint>
#include <cstddef>

typedef __bf16 bf16;
typedef __attribute__((ext_vector_type(8))) __bf16 bf16x8;
typedef __attribute__((ext_vector_type(4))) __bf16 bf16x4;
typedef __attribute__((ext_vector_type(4))) float f32x4;

// ---------------------------------------------------------------------------
// async global->LDS, 16B per lane (wave-uniform LDS base + lane*16)
__device__ __forceinline__ void gload_lds16(const void* g, void* l) {
  __builtin_amdgcn_global_load_lds(
      (const __attribute__((address_space(1))) uint32_t*)(uintptr_t)g,
      (__attribute__((address_space(3))) uint32_t*)(uintptr_t)l, 16, 0, 0);
}

// ---------------------------------------------------------------------------
// Batched NT GEMM, up to 4 problems per launch via blockIdx.z.
// PIPE=0: classic 2-barrier loop (for >=3 blocks/CU residency, cross-block
//         overlap hides load latency — m114).
// PIPE=1: double-buffered LDS + counted vmcnt(4) + raw s_barrier: next tile's
//         global_load_lds stays in flight across the barrier while current
//         tile's MFMAs run. Targets grid-limited batches (~2 blocks/CU) where
//         the vmcnt(0) drain is fully exposed (~1220cy/step vs ~310cy MFMA).
// C[M=4096, Npad] = act(A[M,K] * Bt[Npad,K]^T + bias); act runtime
// (0=none,1=tanh,2=sigmoid). 128x128 tile, BK=32, 4 waves 2x2, 4x4
// mfma_f32_16x16x32_bf16 per wave. Requires K % 64 == 0 (nt even).
struct GProb {
  const bf16* A; const bf16* Bt; const float* bias;
  float* Cf; bf16* Cb;
  int K, Npad, ldcf, ldcb, Ntrue, act;
};
struct GBatch { GProb p[4]; };

#define STAGE_(Ad, Bd, kk) do {                                   \
    gload_lds16(P.A + aoff[0] + (kk), (Ad) + ldsoff[0]);          \
    gload_lds16(P.A + aoff[1] + (kk), (Ad) + ldsoff[1]);          \
    gload_lds16(P.Bt + boff[0] + (kk), (Bd) + ldsoff[0]);         \
    gload_lds16(P.Bt + boff[1] + (kk), (Bd) + ldsoff[1]);         \
  } while (0)

#define COMPUTE_(Ab, Bb) do {                                     \
    bf16x8 av[4], bv[4];                                          \
    _Pragma("unroll")                                             \
    for (int i_ = 0; i_ < 4; ++i_) av[i_] = *(const bf16x8*)((Ab) + afr[i_]); \
    _Pragma("unroll")                                             \
    for (int j_ = 0; j_ < 4; ++j_) bv[j_] = *(const bf16x8*)((Bb) + bfr[j_]); \
    _Pragma("unroll")                                             \
    for (int i_ = 0; i_ < 4; ++i_)                                \
      _Pragma("unroll")                                           \
      for (int j_ = 0; j_ < 4; ++j_)                              \
        acc[i_][j_] = __builtin_amdgcn_mfma_f32_16x16x32_bf16(av[i_], bv[j_], acc[i_][j_], 0, 0, 0); \
  } while (0)

template<int PIPE>
__global__ __launch_bounds__(256, 2)
void gemm_nt_batch(GBatch b)
{
  const GProb P = b.p[blockIdx.z];
  const long bn = (long)blockIdx.x * 128;
  if (bn >= P.Npad) return;          // uniform whole-block exit (before any barrier)

  __shared__ __align__(16) bf16 As0[128 * 32];
  __shared__ __align__(16) bf16 Bs0[128 * 32];

  const int K    = P.K;
  const int tid  = threadIdx.x;
  const int lane = tid & 63, wave = tid >> 6;
  const int wr = wave >> 1, wc = wave & 1;
  const int l15 = lane & 15, quad = lane >> 4;
  const long bm = (long)blockIdx.y * 128;

  // staging: slot = s*256 + tid; row=slot/4, chunk-slot=slot%4,
  // global chunk = cslot ^ (row&3)  (XOR swizzle; LDS slot order == lane order)
  long aoff[2], boff[2];
  int ldsoff[2];
#pragma unroll
  for (int s = 0; s < 2; ++s) {
    int slot = s * 256 + tid;
    int row = slot >> 2, cs = slot & 3;
    int gc = cs ^ (row & 3);
    aoff[s] = (bm + row) * (long)K + gc * 8;
    boff[s] = (bn + row) * (long)K + gc * 8;
    ldsoff[s] = (s * 256 + wave * 64) * 8;   // wave-uniform base (elements)
  }

  // fragment LDS offsets: row r needs chunk q at slot q^(r&3); r&3 == lane&3
  const int cfr = (quad ^ (lane & 3)) * 8;
  int afr[4], bfr[4];
#pragma unroll
  for (int i = 0; i < 4; ++i) {
    afr[i] = (wr * 64 + i * 16 + l15) * 32 + cfr;
    bfr[i] = (wc * 64 + i * 16 + l15) * 32 + cfr;
  }

  f32x4 acc[4][4];
#pragma unroll
  for (int i = 0; i < 4; ++i)
#pragma unroll
    for (int j = 0; j < 4; ++j) acc[i][j] = {0.f, 0.f, 0.f, 0.f};

  if constexpr (PIPE == 0) {
    for (int k0 = 0; k0 < K; k0 += 32) {
      __syncthreads();                       // protect LDS from previous readers
      STAGE_(As0, Bs0, k0);
      __syncthreads();                       // compiler drains vmcnt before barrier
      COMPUTE_(As0, Bs0);
    }
  } else {
    __shared__ __align__(16) bf16 As1[128 * 32];
    __shared__ __align__(16) bf16 Bs1[128 * 32];
    const int nt = K >> 5;                   // even for all shapes used
    STAGE_(As0, Bs0, 0);                     // prologue: tile 0 -> buf0
    for (int t = 0; t < nt; t += 2) {
      STAGE_(As1, Bs1, (t + 1) * 32);        // buf1 last read 2 phases ago (barrier-covered)
      asm volatile("s_waitcnt vmcnt(4)" ::: "memory");   // oldest 4 (buf0) landed
      __builtin_amdgcn_s_barrier();
      __builtin_amdgcn_sched_barrier(0);
      COMPUTE_(As0, Bs0);
      asm volatile("s_waitcnt lgkmcnt(0)" ::: "memory"); // buf0 reads retired
      __builtin_amdgcn_s_barrier();          // all waves done with buf0
      if (t + 2 < nt) {
        STAGE_(As0, Bs0, (t + 2) * 32);
        asm volatile("s_waitcnt vmcnt(4)" ::: "memory"); // oldest 4 (buf1) landed
      } else {
        asm volatile("s_waitcnt vmcnt(0)" ::: "memory");
      }
      __builtin_amdgcn_s_barrier();
      __builtin_amdgcn_sched_barrier(0);
      COMPUTE_(As1, Bs1);
      asm volatile("s_waitcnt lgkmcnt(0)" ::: "memory");
      __builtin_amdgcn_s_barrier();          // all waves done with buf1
    }
  }

  // epilogue: C/D layout col=lane&15, row=quad*4+reg
  const long row0 = bm + wr * 64 + quad * 4;
  const long col0 = bn + wc * 64 + l15;
  const int act = P.act;
#pragma unroll
  for (int i = 0; i < 4; ++i) {
#pragma unroll
    for (int j = 0; j < 4; ++j) {
      long c = col0 + j * 16;
      float bb = P.bias ? P.bias[c] : 0.f;
#pragma unroll
      for (int t = 0; t < 4; ++t) {
        long r = row0 + i * 16 + t;
        float v = acc[i][j][t] + bb;
        if (act == 1) v = tanhf(v);
        else if (act == 2) v = 1.f / (1.f + __expf(-v));
        if (P.Cf && c < P.Ntrue) P.Cf[r * P.ldcf + c] = v;
        if (P.Cb) P.Cb[r * P.ldcb + c] = (bf16)v;
      }
    }
  }
}

// ---------------------------------------------------------------------------
// Batched padded transpose: dst[P x Q] = src^T zero-padded.
struct TrBatch {
  const void* src[14]; bf16* dst[14];
  int R[14], C[14], Q[14], nbx[14], isb[14];
  int blkStart[15];
  int nprob;
};

__global__ void tr_batch(TrBatch a)
{
  __shared__ float tile[32][33];
  int pi = 0, b = blockIdx.x;
  while (b >= a.blkStart[pi + 1]) ++pi;
  const int rel = b - a.blkStart[pi];
  const int nbx = a.nbx[pi];
  const int q0 = (rel % nbx) * 32;       // src-row block
  const int p0 = (rel / nbx) * 32;       // src-col block
  const int R = a.R[pi], C = a.C[pi], Q = a.Q[pi];
  const bool isb = a.isb[pi] != 0;
  const void* src = a.src[pi];
  const int tx = threadIdx.x & 31, ty = threadIdx.x >> 5;
#pragma unroll
  for (int y = ty; y < 32; y += 8) {
    int r = q0 + y, c = p0 + tx;
    float v = 0.f;
    if (r < R && c < C)
      v = isb ? (float)((const bf16*)src)[(long)r * C + c]
              : ((const float*)src)[(long)r * C + c];
    tile[y][tx] = v;
  }
  __syncthreads();
  bf16* dst = a.dst[pi];
#pragma unroll
  for (int y = ty; y < 32; y += 8)
    dst[(long)(p0 + y) * Q + (q0 + tx)] = (bf16)tile[tx][y];
}

// fp32 -> bf16, two buffers per launch (blockIdx.z), n % 4 == 0
struct CvtB { const float* s[2]; bf16* d[2]; };
__global__ void cvt_batch(CvtB cb, long n)
{
  const float* s = cb.s[blockIdx.z];
  bf16* d = cb.d[blockIdx.z];
  long i = ((long)blockIdx.x * blockDim.x + threadIdx.x) * 4;
  if (i >= n) return;
  float4 v = *(const float4*)(s + i);
  bf16x4 o = {(bf16)v.x, (bf16)v.y, (bf16)v.z, (bf16)v.w};
  *(bf16x4*)(d + i) = o;
}

// z = (we0*h20 + we1*h21)/(we0+we1); fp32 [4096,819] out + bf16 [4096,896]
__global__ void zkern(const float* __restrict__ h20, const float* __restrict__ h21,
                      const float* __restrict__ we, float* __restrict__ zout,
                      bf16* __restrict__ zb)
{
  const int n = blockIdx.x;
  const float w0 = we[n * 2], w1 = we[n * 2 + 1];
  const float inv = 1.f / (w0 + w1);
  for (int c = threadIdx.x; c < 896; c += 256) {
    float v = (w0 * h20[(long)n * 896 + c] + w1 * h21[(long)n * 896 + c]) * inv;
    zb[(long)n * 896 + c] = (bf16)v;
    if (c < 819) zout[(long)n * 819 + c] = v;
  }
}

// Student-t q per row (one wave per row). NO atomics — colsum done separately.
__global__ void qkern(const float* __restrict__ z, const float* __restrict__ cl,
                      float* __restrict__ qout)
{
  const int n = blockIdx.x;
  const int lane = threadIdx.x;
  float d0 = 0, d1 = 0, d2 = 0, d3 = 0, d4 = 0;
  for (int s = lane; s < 819; s += 64) {
    float zv = z[(long)n * 819 + s];
    float t0 = zv - cl[0 * 819 + s]; d0 += t0 * t0;
    float t1 = zv - cl[1 * 819 + s]; d1 += t1 * t1;
    float t2 = zv - cl[2 * 819 + s]; d2 += t2 * t2;
    float t3 = zv - cl[3 * 819 + s]; d3 += t3 * t3;
    float t4 = zv - cl[4 * 819 + s]; d4 += t4 * t4;
  }
#pragma unroll
  for (int off = 32; off > 0; off >>= 1) {
    d0 += __shfl_xor(d0, off);
    d1 += __shfl_xor(d1, off);
    d2 += __shfl_xor(d2, off);
    d3 += __shfl_xor(d3, off);
    d4 += __shfl_xor(d4, off);
  }
  if (lane == 0) {
    float q0 = 1.f / (1.f + d0), q1 = 1.f / (1.f + d1), q2 = 1.f / (1.f + d2);
    float q3 = 1.f / (1.f + d3), q4 = 1.f / (1.f + d4);
    float inv = 1.f / (q0 + q1 + q2 + q3 + q4);
    float* qr = qout + (long)n * 5;
    qr[0] = q0 * inv; qr[1] = q1 * inv; qr[2] = q2 * inv;
    qr[3] = q3 * inv; qr[4] = q4 * inv;
  }
}

__global__ void colsum_kern(const float* __restrict__ q, float* __restrict__ colsum)
{
  __shared__ float red[256];
  const int k = blockIdx.x;
  float s = 0.f;
  for (int n = threadIdx.x; n < 4096; n += 256) s += q[(long)n * 5 + k];
  red[threadIdx.x] = s;
  __syncthreads();
  for (int w = 128; w > 0; w >>= 1) {
    if (threadIdx.x < w) red[threadIdx.x] += red[threadIdx.x + w];
    __syncthreads();
  }
  if (threadIdx.x == 0) colsum[k] = red[0];
}

__global__ void pkern(const float* __restrict__ q, const float* __restrict__ colsum,
                      float* __restrict__ p)
{
  int n = blockIdx.x * blockDim.x + threadIdx.x;
  if (n >= 4096) return;
  float w[5], s = 0.f;
#pragma unroll
  for (int k = 0; k < 5; ++k) {
    float qv = q[(long)n * 5 + k];
    w[k] = qv * qv / colsum[k];
    s += w[k];
  }
  float inv = 1.f / s;
#pragma unroll
  for (int k = 0; k < 5; ++k) p[(long)n * 5 + k] = w[k] * inv;
}

struct BiasArgs {
  const float* src[8];
  float* dst[8];
  int n[8];
  int np[8];
};

__global__ void biaspad(BiasArgs a)
{
  int b = blockIdx.x;
  for (int i = threadIdx.x; i < a.np[b]; i += blockDim.x)
    a.dst[b][i] = (i < a.n[b]) ? a.src[b][i] : 0.f;
}

// ---------------------------------------------------------------------------
extern "C" void kernel_launch(void* const* d_in, const int* in_sizes, int n_in,
                              void* d_out, int out_size, void* d_ws, size_t ws_size,
                              hipStream_t stream)
{
  (void)in_sizes; (void)n_in; (void)out_size; (void)ws_size;
  const float* x0    = (const float*)d_in[0];
  const float* x1    = (const float*)d_in[1];
  const float* we    = (const float*)d_in[2];
  const float* g0    = (const float*)d_in[3];
  const float* g1    = (const float*)d_in[4];
  const float* We1_0 = (const float*)d_in[5];
  const float* be1_0 = (const float*)d_in[6];
  const float* We2_0 = (const float*)d_in[7];
  const float* be2_0 = (const float*)d_in[8];
  const float* We1_1 = (const float*)d_in[9];
  const float* be1_1 = (const float*)d_in[10];
  const float* We2_1 = (const float*)d_in[11];
  const float* be2_1 = (const float*)d_in[12];
  const float* Wd1_0 = (const float*)d_in[13];
  const float* bd1_0 = (const float*)d_in[14];
  const float* Wd2_0 = (const float*)d_in[15];
  const float* bd2_0 = (const float*)d_in[16];
  const float* Wd1_1 = (const float*)d_in[17];
  const float* bd1_1 = (const float*)d_in[18];
  const float* Wd2_1 = (const float*)d_in[19];
  const float* bd2_1 = (const float*)d_in[20];
  const float* Ww0   = (const float*)d_in[21];
  const float* Ww1   = (const float*)d_in[22];
  const float* Wf0   = (const float*)d_in[23];
  const float* Wf1   = (const float*)d_in[24];
  const float* clus  = (const float*)d_in[25];
  float* out = (float*)d_out;

  const size_t OFF_REC0 = 0;
  const size_t OFF_REC1 = 4194304;
  const size_t OFF_ADJ0 = 9437184;
  const size_t OFF_ADJ1 = 26214400;
  const size_t OFF_Z    = 42991616;
  const size_t OFF_P    = 46346240;
  const size_t OFF_Q    = 46366720;
  const size_t OFF_CL   = 46387200;

  char* ws = (char*)d_ws;
  size_t off = 0;
  auto alloc = [&](size_t bytes) -> void* {
    off = (off + 255) & ~(size_t)255;
    void* p = ws + off;
    off += bytes;
    return p;
  };
  const long N = 4096;
  bf16* g0b   = (bf16*)alloc((size_t)N * 4096 * 2);
  bf16* g1b   = (bf16*)alloc((size_t)N * 4096 * 2);
  bf16* BTe10 = (bf16*)alloc((size_t)896 * 1024 * 2);
  bf16* BTe20 = (bf16*)alloc((size_t)896 * 896 * 2);
  bf16* BTe11 = (bf16*)alloc((size_t)1024 * 1280 * 2);
  bf16* BTe21 = (bf16*)alloc((size_t)896 * 1024 * 2);
  bf16* BTd10 = (bf16*)alloc((size_t)896 * 896 * 2);
  bf16* BTd20 = (bf16*)alloc((size_t)1024 * 896 * 2);
  bf16* BTd11 = (bf16*)alloc((size_t)1024 * 896 * 2);
  bf16* BTd21 = (bf16*)alloc((size_t)1280 * 1024 * 2);
  bf16* BTw0  = (bf16*)alloc((size_t)896 * 896 * 2);
  bf16* BTw1  = (bf16*)alloc((size_t)896 * 896 * 2);
  bf16* BTf0  = (bf16*)alloc((size_t)896 * 896 * 2);
  bf16* BTf1  = (bf16*)alloc((size_t)896 * 896 * 2);
  float* pbe10 = (float*)alloc(896 * 4);
  float* pbe20 = (float*)alloc(896 * 4);
  float* pbe11 = (float*)alloc(1024 * 4);
  float* pbe21 = (float*)alloc(896 * 4);
  float* pbd10 = (float*)alloc(896 * 4);
  float* pbd20 = (float*)alloc(1024 * 4);
  float* pbd11 = (float*)alloc(1024 * 4);
  float* pbd21 = (float*)alloc(1280 * 4);
  float* h20f  = (float*)alloc((size_t)N * 896 * 4);
  float* h21f  = (float*)alloc((size_t)N * 896 * 4);
  bf16* zb     = (bf16*)alloc((size_t)N * 896 * 2);
  float* colsum = (float*)alloc(64);
  // transposed-operand buffers (reused 3-4x along the stream order)
  bf16* xT0 = (bf16*)alloc((size_t)1024 * 4096 * 2);  // x0^T / h1_0^T / t0^T / hr0^T
  bf16* xT1 = (bf16*)alloc((size_t)1280 * 4096 * 2);  // x1^T / h1_1^T / t1^T / hr1^T
  bf16* u0  = (bf16*)alloc((size_t)N * 1024 * 2);     // u0 / r0 / rin0
  bf16* u1  = (bf16*)alloc((size_t)N * 1280 * 2);     // u1 / r1 / rin1
  bf16* h0  = (bf16*)alloc((size_t)N * 896 * 2);      // h1_0 / v0 / hr0
  bf16* h1b = (bf16*)alloc((size_t)N * 1024 * 2);     // h1_1 / v1 / hr1
  bf16* y0  = (bf16*)alloc((size_t)N * 896 * 2);
  bf16* y1  = (bf16*)alloc((size_t)N * 896 * 2);
  bf16* t0b = (bf16*)alloc((size_t)N * 896 * 2);
  bf16* t1b = (bf16*)alloc((size_t)N * 896 * 2);

  // ---- input conversions (one launch) ------------------------------------
  {
    CvtB cb;
    cb.s[0] = g0; cb.d[0] = g0b;
    cb.s[1] = g1; cb.d[1] = g1b;
    cvt_batch<<<dim3(16384, 1, 2), 256, 0, stream>>>(cb, N * 4096);
  }

  // ---- all 14 transposes in one launch ------------------------------------
  {
    TrBatch tb{};
    tb.nprob = 0; tb.blkStart[0] = 0;
    auto addTr = [&](const void* s, bf16* d, int R, int C, int P, int Q, int isb) {
      int i = tb.nprob++;
      tb.src[i] = s; tb.dst[i] = d;
      tb.R[i] = R; tb.C[i] = C; tb.Q[i] = Q; tb.isb[i] = isb;
      tb.nbx[i] = Q / 32;
      tb.blkStart[i + 1] = tb.blkStart[i] + (Q / 32) * (P / 32);
    };
    addTr(x0, xT0, 4096, 1024, 1024, 4096, 0);
    addTr(x1, xT1, 4096, 1280, 1280, 4096, 0);
    addTr(We1_0, BTe10, 1024, 819, 896, 1024, 0);
    addTr(We2_0, BTe20, 819, 819, 896, 896, 0);
    addTr(We1_1, BTe11, 1280, 1024, 1024, 1280, 0);
    addTr(We2_1, BTe21, 1024, 819, 896, 1024, 0);
    addTr(Wd1_0, BTd10, 819, 819, 896, 896, 0);
    addTr(Wd2_0, BTd20, 819, 1024, 1024, 896, 0);
    addTr(Wd1_1, BTd11, 819, 1024, 1024, 896, 0);
    addTr(Wd2_1, BTd21, 1024, 1280, 1280, 1024, 0);
    addTr(Ww0, BTw0, 819, 819, 896, 896, 0);
    addTr(Ww1, BTw1, 819, 819, 896, 896, 0);
    addTr(Wf0, BTf0, 819, 819, 896, 896, 0);
    addTr(Wf1, BTf1, 819, 819, 896, 896, 0);
    tr_batch<<<tb.blkStart[tb.nprob], 256, 0, stream>>>(tb);
  }

  BiasArgs ba;
  {
    const float* bsrc[8] = {be1_0, be2_0, be1_1, be2_1, bd1_0, bd2_0, bd1_1, bd2_1};
    float* bdst[8] = {pbe10, pbe20, pbe11, pbe21, pbd10, pbd20, pbd11, pbd21};
    int bn_[8] = {819, 819, 1024, 819, 819, 1024, 1024, 1280};
    int bnp[8] = {896, 896, 1024, 896, 896, 1024, 1024, 1280};
    for (int i = 0; i < 8; ++i) { ba.src[i] = bsrc[i]; ba.dst[i] = bdst[i]; ba.n[i] = bn_[i]; ba.np[i] = bnp[i]; }
  }
  biaspad<<<8, 256, 0, stream>>>(ba);

  // ---- batched GEMM helpers ----------------------------------------------
  GBatch gb{};
  int np = 0, maxN = 0;
  auto beg = [&]() { np = 0; maxN = 0; };
  auto add = [&](const bf16* A, const bf16* Bt, const float* bias,
                 float* Cf, int ldcf, bf16* Cb, int ldcb,
                 int K, int Npad, int Ntrue, int act) {
    gb.p[np].A = A; gb.p[np].Bt = Bt; gb.p[np].bias = bias;
    gb.p[np].Cf = Cf; gb.p[np].Cb = Cb;
    gb.p[np].K = K; gb.p[np].Npad = Npad;
    gb.p[np].ldcf = ldcf; gb.p[np].ldcb = ldcb;
    gb.p[np].Ntrue = Ntrue; gb.p[np].act = act;
    ++np;
    if (Npad > maxN) maxN = Npad;
  };
  auto go = [&]() {
    int active = 0;
    for (int i = 0; i < np; ++i) active += gb.p[i].Npad / 128;
    dim3 grid(maxN / 128, 32, np);
    if (active * 32 < 768)           // < 3 blocks/CU -> latency-bound -> pipelined
      gemm_nt_batch<1><<<grid, 256, 0, stream>>>(gb);
    else
      gemm_nt_batch<0><<<grid, 256, 0, stream>>>(gb);
  };
  auto trb2 = [&](const bf16* s0, int C0, const bf16* s1, int C1) {
    TrBatch tb{};
    tb.nprob = 2; tb.blkStart[0] = 0;
    tb.src[0] = s0; tb.dst[0] = xT0; tb.R[0] = 4096; tb.C[0] = C0; tb.Q[0] = 4096;
    tb.isb[0] = 1; tb.nbx[0] = 128; tb.blkStart[1] = 128 * (C0 / 32);
    tb.src[1] = s1; tb.dst[1] = xT1; tb.R[1] = 4096; tb.C[1] = C1; tb.Q[1] = 4096;
    tb.isb[1] = 1; tb.nbx[1] = 128; tb.blkStart[2] = tb.blkStart[1] + 128 * (C1 / 32);
    tr_batch<<<tb.blkStart[2], 256, 0, stream>>>(tb);
  };

  // ---- encoders (0 || 1) -------------------------------------------------
  beg();  // A: u = g @ x
  add(g0b, xT0, nullptr, nullptr, 0, u0, 1024, 4096, 1024, 1024, 0);
  add(g1b, xT1, nullptr, nullptr, 0, u1, 1280, 4096, 1280, 1280, 0);
  go();
  beg();  // B: h1 = tanh(u @ We1 + b)
  add(u0, BTe10, pbe10, nullptr, 0, h0, 896, 1024, 896, 896, 1);
  add(u1, BTe11, pbe11, nullptr, 0, h1b, 1024, 1280, 1024, 1024, 1);
  go();
  trb2(h0, 896, h1b, 1024);                                  // h1^T
  beg();  // C: v = g @ h1
  add(g0b, xT0, nullptr, nullptr, 0, h0, 896, 4096, 896, 896, 0);
  add(g1b, xT1, nullptr, nullptr, 0, h1b, 1024, 4096, 1024, 1024, 0);
  go();
  beg();  // D: h2 = tanh(v @ We2 + b)  (fp32 out)
  add(h0, BTe20, pbe20, h20f, 896, nullptr, 0, 896, 896, 896, 1);
  add(h1b, BTe21, pbe21, h21f, 896, nullptr, 0, 1024, 896, 896, 1);
  go();

  // ---- z -----------------------------------------------------------------
  zkern<<<4096, 256, 0, stream>>>(h20f, h21f, we, out + OFF_Z, zb);

  // ---- four z-projections in one launch ----------------------------------
  beg();  // E: y0, y1 (act0), t0, t1 (act1)
  add(zb, BTw0, nullptr, nullptr, 0, y0, 896, 896, 896, 896, 0);
  add(zb, BTw1, nullptr, nullptr, 0, y1, 896, 896, 896, 896, 0);
  add(zb, BTf0, nullptr, nullptr, 0, t0b, 896, 896, 896, 896, 1);
  add(zb, BTf1, nullptr, nullptr, 0, t1b, 896, 896, 896, 896, 1);
  go();

  // ---- adj (F) and decoder-start (G) merged: both depend only on E -------
  trb2(t0b, 896, t1b, 896);                                  // t^T
  beg();  // G first (scheduled early), then F fills the machine
  add(g0b, xT0, nullptr, nullptr, 0, u0, 896, 4096, 896, 896, 0);      // r0 = g0 t0
  add(g1b, xT1, nullptr, nullptr, 0, u1, 896, 4096, 896, 896, 0);      // r1 = g1 t1
  add(y0, zb, nullptr, out + OFF_ADJ0, 4096, nullptr, 0, 896, 4096, 4096, 2);
  add(y1, zb, nullptr, out + OFF_ADJ1, 4096, nullptr, 0, 896, 4096, 4096, 2);
  go();

  // ---- feature decoders (0 || 1) -----------------------------------------
  beg();  // H: hr = tanh(r @ Wd1 + b)
  add(u0, BTd10, pbd10, nullptr, 0, h0, 896, 896, 896, 896, 1);
  add(u1, BTd11, pbd11, nullptr, 0, h1b, 1024, 896, 1024, 1024, 1);
  go();
  trb2(h0, 896, h1b, 1024);                                  // hr^T
  beg();  // I: rin = g @ hr
  add(g0b, xT0, nullptr, nullptr, 0, u0, 896, 4096, 896, 896, 0);
  add(g1b, xT1, nullptr, nullptr, 0, u1, 1024, 4096, 1024, 1024, 0);
  go();
  beg();  // J: rec = tanh(rin @ Wd2 + b)  (fp32 out)
  add(u0, BTd20, pbd20, out + OFF_REC0, 1024, nullptr, 0, 896, 1024, 1024, 1);
  add(u1, BTd21, pbd21, out + OFF_REC1, 1280, nullptr, 0, 1024, 1280, 1280, 1);
  go();

  // ---- q / p / cluster ---------------------------------------------------
  qkern<<<4096, 64, 0, stream>>>(out + OFF_Z, clus, out + OFF_Q);
  colsum_kern<<<5, 256, 0, stream>>>(out + OFF_Q, colsum);
  pkern<<<16, 256, 0, stream>>>(out + OFF_Q, colsum, out + OFF_P);
  hipMemcpyAsync(out + OFF_CL, (const void*)clus, 4095 * sizeof(float),
                 hipMemcpyDeviceToDevice, stream);
}

// Round 3
// 1272.356 us; speedup vs baseline: 1.0348x; 1.0348x over previous
//
#include <hip/hip_runtime.h>
#include <hip/hip_bf16.h>
#include <cstdint>
#include <cstddef>

typedef __bf16 bf16;
typedef __attribute__((ext_vector_type(8))) __bf16 bf16x8;
typedef __attribute__((ext_vector_type(4))) __bf16 bf16x4;
typedef __attribute__((ext_vector_type(4))) float f32x4;

// ---------------------------------------------------------------------------
// async global->LDS, 16B per lane (wave-uniform LDS base + lane*16)
__device__ __forceinline__ void gload_lds16(const void* g, void* l) {
  __builtin_amdgcn_global_load_lds(
      (const __attribute__((address_space(1))) uint32_t*)(uintptr_t)g,
      (__attribute__((address_space(3))) uint32_t*)(uintptr_t)l, 16, 0, 0);
}

// ---------------------------------------------------------------------------
// Batched NT GEMM, problems selected by blockIdx.z.
// SPLIT=1: fused epilogue (bias/act, fp32/bf16 stores).
// SPLIT=2: split-K over 2 blocks (z = prob*2 + kz); raw fp32 partials to
//   P.Cp[kz][4096][Npad]; combine_batch finishes. Purpose: K=4096 batches
//   have 448-576 blocks = 2.25/CU (grid-limited, MfmaUtil 22%); doubling
//   blocks -> 3.5-3.75/CU so cross-block overlap hides the vmcnt drain
//   (m102: 320 TF @1blk/CU vs 833 @4).
// XOR swizzle includes (row>>2)&3: the old (row&3)-only swizzle left lanes
// {0,4,8,12} of each quad on the same 16B chunk -> 4-way ds_read_b128 bank
// conflict (SQ_LDS_BANK_CONFLICT 9.4e6/dispatch). Now max 2-way (free, m136).
struct GProb {
  const bf16* A; const bf16* Bt; const float* bias;
  float* Cf; bf16* Cb; float* Cp;
  int K, Npad, ldcf, ldcb, Ntrue, act;
};
struct GBatch { GProb p[4]; };

template<int SPLIT>
__global__ __launch_bounds__(256, 2)
void gemm_nt_batch(GBatch b)
{
  const int prob = (SPLIT == 2) ? ((int)blockIdx.z >> 1) : (int)blockIdx.z;
  const int kz   = (SPLIT == 2) ? ((int)blockIdx.z & 1) : 0;
  const GProb P = b.p[prob];
  const long bn = (long)blockIdx.x * 128;
  if (bn >= P.Npad) return;          // uniform whole-block exit (before any barrier)

  __shared__ __align__(16) bf16 As[128 * 32];
  __shared__ __align__(16) bf16 Bs[128 * 32];

  const int K    = P.K;
  const int tid  = threadIdx.x;
  const int lane = tid & 63, wave = tid >> 6;
  const int wr = wave >> 1, wc = wave & 1;
  const int l15 = lane & 15, quad = lane >> 4;
  const long bm = (long)blockIdx.y * 128;

  // staging: slot = s*256 + tid; row=slot/4, chunk-slot=slot%4,
  // global chunk = cslot ^ (row&3) ^ ((row>>2)&3)  (involution; LDS slot
  // order == lane order as required by global_load_lds)
  long aoff[2], boff[2];
  int ldsoff[2];
#pragma unroll
  for (int s = 0; s < 2; ++s) {
    int slot = s * 256 + tid;
    int row = slot >> 2, cs = slot & 3;
    int gc = (cs ^ (row & 3) ^ ((row >> 2) & 3)) & 3;
    aoff[s] = (bm + row) * (long)K + gc * 8;
    boff[s] = (bn + row) * (long)K + gc * 8;
    ldsoff[s] = (s * 256 + wave * 64) * 8;   // wave-uniform base (elements)
  }

  // fragment reads: row r needs global chunk q at slot q^(r&3)^((r>>2)&3);
  // r&3 == lane&3, (r>>2)&3 == (lane>>2)&3 for r = i*16 + (lane&15)
  const int cfr = ((quad ^ (lane & 3) ^ ((lane >> 2) & 3)) & 3) * 8;
  int afr[4], bfr[4];
#pragma unroll
  for (int i = 0; i < 4; ++i) {
    afr[i] = (wr * 64 + i * 16 + l15) * 32 + cfr;
    bfr[i] = (wc * 64 + i * 16 + l15) * 32 + cfr;
  }

  f32x4 acc[4][4];
#pragma unroll
  for (int i = 0; i < 4; ++i)
#pragma unroll
    for (int j = 0; j < 4; ++j) acc[i][j] = {0.f, 0.f, 0.f, 0.f};

  const int Kseg = K / SPLIT;
  const int kbeg = kz * Kseg;
  for (int k0 = kbeg; k0 < kbeg + Kseg; k0 += 32) {
    __syncthreads();                       // protect LDS from previous readers
    gload_lds16(P.A + aoff[0] + k0, As + ldsoff[0]);
    gload_lds16(P.A + aoff[1] + k0, As + ldsoff[1]);
    gload_lds16(P.Bt + boff[0] + k0, Bs + ldsoff[0]);
    gload_lds16(P.Bt + boff[1] + k0, Bs + ldsoff[1]);
    __syncthreads();                       // compiler drains vmcnt before barrier

    bf16x8 av[4], bv[4];
#pragma unroll
    for (int i = 0; i < 4; ++i) av[i] = *(const bf16x8*)(As + afr[i]);
#pragma unroll
    for (int j = 0; j < 4; ++j) bv[j] = *(const bf16x8*)(Bs + bfr[j]);
#pragma unroll
    for (int i = 0; i < 4; ++i)
#pragma unroll
      for (int j = 0; j < 4; ++j)
        acc[i][j] = __builtin_amdgcn_mfma_f32_16x16x32_bf16(av[i], bv[j], acc[i][j], 0, 0, 0);
  }

  // epilogue: C/D layout col=lane&15, row=quad*4+reg
  const long row0 = bm + wr * 64 + quad * 4;
  const long col0 = bn + wc * 64 + l15;
  if constexpr (SPLIT == 2) {
    float* Cp = P.Cp + (long)kz * 4096 * P.Npad;
#pragma unroll
    for (int i = 0; i < 4; ++i)
#pragma unroll
      for (int j = 0; j < 4; ++j)
#pragma unroll
        for (int t = 0; t < 4; ++t)
          Cp[(row0 + i * 16 + t) * (long)P.Npad + col0 + j * 16] = acc[i][j][t];
  } else {
    const int act = P.act;
#pragma unroll
    for (int i = 0; i < 4; ++i) {
#pragma unroll
      for (int j = 0; j < 4; ++j) {
        long c = col0 + j * 16;
        float bb = P.bias ? P.bias[c] : 0.f;
#pragma unroll
        for (int t = 0; t < 4; ++t) {
          long r = row0 + i * 16 + t;
          float v = acc[i][j][t] + bb;
          if (act == 1) v = tanhf(v);
          else if (act == 2) v = 1.f / (1.f + __expf(-v));
          if (P.Cf && c < P.Ntrue) P.Cf[r * P.ldcf + c] = v;
          if (P.Cb) P.Cb[r * P.ldcb + c] = (bf16)v;
        }
      }
    }
  }
}

// ---------------------------------------------------------------------------
// combine: out = act(part[0] + part[1] + bias); fp32 and/or bf16 stores.
// One block per row, 256 threads x float4 covers Npad <= 1024.
struct CProb {
  const float* part; const float* bias;
  float* Cf; bf16* Cb;
  int Npad, ldcf, ldcb, Ntrue, act;
};
struct CBatch { CProb p[2]; };

__global__ void combine_batch(CBatch cb)
{
  const CProb P = cb.p[blockIdx.z];
  const int row = blockIdx.x;
  const int c4 = threadIdx.x * 4;
  if (c4 >= P.Npad) return;
  const long base = (long)row * P.Npad + c4;
  float4 a = *(const float4*)(P.part + base);
  float4 b = *(const float4*)(P.part + (long)4096 * P.Npad + base);
  float v[4] = {a.x + b.x, a.y + b.y, a.z + b.z, a.w + b.w};
  if (P.bias) {
    float4 bi = *(const float4*)(P.bias + c4);
    v[0] += bi.x; v[1] += bi.y; v[2] += bi.z; v[3] += bi.w;
  }
#pragma unroll
  for (int t = 0; t < 4; ++t) {
    if (P.act == 1) v[t] = tanhf(v[t]);
    else if (P.act == 2) v[t] = 1.f / (1.f + __expf(-v[t]));
  }
  if (P.Cf && c4 < P.Ntrue) {
    float* o = P.Cf + (long)row * P.ldcf + c4;
    o[0] = v[0]; o[1] = v[1]; o[2] = v[2]; o[3] = v[3];
  }
  if (P.Cb) {
    bf16x4 o = {(bf16)v[0], (bf16)v[1], (bf16)v[2], (bf16)v[3]};
    *(bf16x4*)(P.Cb + (long)row * P.ldcb + c4) = o;
  }
}

// ---------------------------------------------------------------------------
// Batched padded transpose: dst[P x Q] = src^T zero-padded.
struct TrBatch {
  const void* src[14]; bf16* dst[14];
  int R[14], C[14], Q[14], nbx[14], isb[14];
  int blkStart[15];
  int nprob;
};

__global__ void tr_batch(TrBatch a)
{
  __shared__ float tile[32][33];
  int pi = 0, b = blockIdx.x;
  while (b >= a.blkStart[pi + 1]) ++pi;
  const int rel = b - a.blkStart[pi];
  const int nbx = a.nbx[pi];
  const int q0 = (rel % nbx) * 32;       // src-row block
  const int p0 = (rel / nbx) * 32;       // src-col block
  const int R = a.R[pi], C = a.C[pi], Q = a.Q[pi];
  const bool isb = a.isb[pi] != 0;
  const void* src = a.src[pi];
  const int tx = threadIdx.x & 31, ty = threadIdx.x >> 5;
#pragma unroll
  for (int y = ty; y < 32; y += 8) {
    int r = q0 + y, c = p0 + tx;
    float v = 0.f;
    if (r < R && c < C)
      v = isb ? (float)((const bf16*)src)[(long)r * C + c]
              : ((const float*)src)[(long)r * C + c];
    tile[y][tx] = v;
  }
  __syncthreads();
  bf16* dst = a.dst[pi];
#pragma unroll
  for (int y = ty; y < 32; y += 8)
    dst[(long)(p0 + y) * Q + (q0 + tx)] = (bf16)tile[tx][y];
}

// fp32 -> bf16, 4 buffers per launch (blockIdx.z), n % 4 == 0
struct CvtB { const float* s[4]; bf16* d[4]; long n[4]; };
__global__ void cvt_batch(CvtB cb)
{
  const float* s = cb.s[blockIdx.z];
  bf16* d = cb.d[blockIdx.z];
  long i = ((long)blockIdx.x * blockDim.x + threadIdx.x) * 4;
  if (i >= cb.n[blockIdx.z]) return;
  float4 v = *(const float4*)(s + i);
  bf16x4 o = {(bf16)v.x, (bf16)v.y, (bf16)v.z, (bf16)v.w};
  *(bf16x4*)(d + i) = o;
}

// z = (we0*h20 + we1*h21)/(we0+we1); fp32 [4096,819] out + bf16 [4096,896]
__global__ void zkern(const float* __restrict__ h20, const float* __restrict__ h21,
                      const float* __restrict__ we, float* __restrict__ zout,
                      bf16* __restrict__ zb)
{
  const int n = blockIdx.x;
  const float w0 = we[n * 2], w1 = we[n * 2 + 1];
  const float inv = 1.f / (w0 + w1);
  for (int c = threadIdx.x; c < 896; c += 256) {
    float v = (w0 * h20[(long)n * 896 + c] + w1 * h21[(long)n * 896 + c]) * inv;
    zb[(long)n * 896 + c] = (bf16)v;
    if (c < 819) zout[(long)n * 819 + c] = v;
  }
}

// Student-t q per row (one wave per row). NO atomics — colsum done separately.
__global__ void qkern(const float* __restrict__ z, const float* __restrict__ cl,
                      float* __restrict__ qout)
{
  const int n = blockIdx.x;
  const int lane = threadIdx.x;
  float d0 = 0, d1 = 0, d2 = 0, d3 = 0, d4 = 0;
  for (int s = lane; s < 819; s += 64) {
    float zv = z[(long)n * 819 + s];
    float t0 = zv - cl[0 * 819 + s]; d0 += t0 * t0;
    float t1 = zv - cl[1 * 819 + s]; d1 += t1 * t1;
    float t2 = zv - cl[2 * 819 + s]; d2 += t2 * t2;
    float t3 = zv - cl[3 * 819 + s]; d3 += t3 * t3;
    float t4 = zv - cl[4 * 819 + s]; d4 += t4 * t4;
  }
#pragma unroll
  for (int off = 32; off > 0; off >>= 1) {
    d0 += __shfl_xor(d0, off);
    d1 += __shfl_xor(d1, off);
    d2 += __shfl_xor(d2, off);
    d3 += __shfl_xor(d3, off);
    d4 += __shfl_xor(d4, off);
  }
  if (lane == 0) {
    float q0 = 1.f / (1.f + d0), q1 = 1.f / (1.f + d1), q2 = 1.f / (1.f + d2);
    float q3 = 1.f / (1.f + d3), q4 = 1.f / (1.f + d4);
    float inv = 1.f / (q0 + q1 + q2 + q3 + q4);
    float* qr = qout + (long)n * 5;
    qr[0] = q0 * inv; qr[1] = q1 * inv; qr[2] = q2 * inv;
    qr[3] = q3 * inv; qr[4] = q4 * inv;
  }
}

__global__ void colsum_kern(const float* __restrict__ q, float* __restrict__ colsum)
{
  __shared__ float red[256];
  const int k = blockIdx.x;
  float s = 0.f;
  for (int n = threadIdx.x; n < 4096; n += 256) s += q[(long)n * 5 + k];
  red[threadIdx.x] = s;
  __syncthreads();
  for (int w = 128; w > 0; w >>= 1) {
    if (threadIdx.x < w) red[threadIdx.x] += red[threadIdx.x + w];
    __syncthreads();
  }
  if (threadIdx.x == 0) colsum[k] = red[0];
}

__global__ void pkern(const float* __restrict__ q, const float* __restrict__ colsum,
                      float* __restrict__ p)
{
  int n = blockIdx.x * blockDim.x + threadIdx.x;
  if (n >= 4096) return;
  float w[5], s = 0.f;
#pragma unroll
  for (int k = 0; k < 5; ++k) {
    float qv = q[(long)n * 5 + k];
    w[k] = qv * qv / colsum[k];
    s += w[k];
  }
  float inv = 1.f / s;
#pragma unroll
  for (int k = 0; k < 5; ++k) p[(long)n * 5 + k] = w[k] * inv;
}

struct BiasArgs {
  const float* src[8];
  float* dst[8];
  int n[8];
  int np[8];
};

__global__ void biaspad(BiasArgs a)
{
  int b = blockIdx.x;
  for (int i = threadIdx.x; i < a.np[b]; i += blockDim.x)
    a.dst[b][i] = (i < a.n[b]) ? a.src[b][i] : 0.f;
}

// ---------------------------------------------------------------------------
extern "C" void kernel_launch(void* const* d_in, const int* in_sizes, int n_in,
                              void* d_out, int out_size, void* d_ws, size_t ws_size,
                              hipStream_t stream)
{
  (void)in_sizes; (void)n_in; (void)out_size; (void)ws_size;
  const float* x0    = (const float*)d_in[0];
  const float* x1    = (const float*)d_in[1];
  const float* we    = (const float*)d_in[2];
  const float* g0    = (const float*)d_in[3];
  const float* g1    = (const float*)d_in[4];
  const float* We1_0 = (const float*)d_in[5];
  const float* be1_0 = (const float*)d_in[6];
  const float* We2_0 = (const float*)d_in[7];
  const float* be2_0 = (const float*)d_in[8];
  const float* We1_1 = (const float*)d_in[9];
  const float* be1_1 = (const float*)d_in[10];
  const float* We2_1 = (const float*)d_in[11];
  const float* be2_1 = (const float*)d_in[12];
  const float* Wd1_0 = (const float*)d_in[13];
  const float* bd1_0 = (const float*)d_in[14];
  const float* Wd2_0 = (const float*)d_in[15];
  const float* bd2_0 = (const float*)d_in[16];
  const float* Wd1_1 = (const float*)d_in[17];
  const float* bd1_1 = (const float*)d_in[18];
  const float* Wd2_1 = (const float*)d_in[19];
  const float* bd2_1 = (const float*)d_in[20];
  const float* Ww0   = (const float*)d_in[21];
  const float* Ww1   = (const float*)d_in[22];
  const float* Wf0   = (const float*)d_in[23];
  const float* Wf1   = (const float*)d_in[24];
  const float* clus  = (const float*)d_in[25];
  float* out = (float*)d_out;

  const size_t OFF_REC0 = 0;
  const size_t OFF_REC1 = 4194304;
  const size_t OFF_ADJ0 = 9437184;
  const size_t OFF_ADJ1 = 26214400;
  const size_t OFF_Z    = 42991616;
  const size_t OFF_P    = 46346240;
  const size_t OFF_Q    = 46366720;
  const size_t OFF_CL   = 46387200;

  char* ws = (char*)d_ws;
  size_t off = 0;
  auto alloc = [&](size_t bytes) -> void* {
    off = (off + 255) & ~(size_t)255;
    void* p = ws + off;
    off += bytes;
    return p;
  };
  const long N = 4096;
  bf16* g0b   = (bf16*)alloc((size_t)N * 4096 * 2);
  bf16* g1b   = (bf16*)alloc((size_t)N * 4096 * 2);
  bf16* x0b   = (bf16*)alloc((size_t)N * 1024 * 2);
  bf16* x1b   = (bf16*)alloc((size_t)N * 1280 * 2);
  bf16* BTe10 = (bf16*)alloc((size_t)896 * 1024 * 2);
  bf16* BTe20 = (bf16*)alloc((size_t)896 * 896 * 2);
  bf16* BTe11 = (bf16*)alloc((size_t)1024 * 1280 * 2);
  bf16* BTe21 = (bf16*)alloc((size_t)896 * 1024 * 2);
  bf16* BTd10 = (bf16*)alloc((size_t)896 * 896 * 2);
  bf16* BTd20 = (bf16*)alloc((size_t)1024 * 896 * 2);
  bf16* BTd11 = (bf16*)alloc((size_t)1024 * 896 * 2);
  bf16* BTd21 = (bf16*)alloc((size_t)1280 * 1024 * 2);
  bf16* BTw0  = (bf16*)alloc((size_t)896 * 896 * 2);
  bf16* BTw1  = (bf16*)alloc((size_t)896 * 896 * 2);
  bf16* BTf0  = (bf16*)alloc((size_t)896 * 896 * 2);
  bf16* BTf1  = (bf16*)alloc((size_t)896 * 896 * 2);
  float* pbe10 = (float*)alloc(896 * 4);
  float* pbe20 = (float*)alloc(896 * 4);
  float* pbe11 = (float*)alloc(1024 * 4);
  float* pbe21 = (float*)alloc(896 * 4);
  float* pbd10 = (float*)alloc(896 * 4);
  float* pbd20 = (float*)alloc(1024 * 4);
  float* pbd11 = (float*)alloc(1024 * 4);
  float* pbd21 = (float*)alloc(1280 * 4);
  float* h20f  = (float*)alloc((size_t)N * 896 * 4);
  float* h21f  = (float*)alloc((size_t)N * 896 * 4);
  bf16* zb     = (bf16*)alloc((size_t)N * 896 * 2);
  float* colsum = (float*)alloc(64);
  bf16* xT0 = (bf16*)alloc((size_t)1024 * 4096 * 2);  // transposed operands, ch 0
  bf16* xT1 = (bf16*)alloc((size_t)1280 * 4096 * 2);  // transposed operands, ch 1
  bf16* u0  = (bf16*)alloc((size_t)N * 1024 * 2);
  bf16* u1  = (bf16*)alloc((size_t)N * 1280 * 2);
  bf16* h0  = (bf16*)alloc((size_t)N * 896 * 2);
  bf16* h1b = (bf16*)alloc((size_t)N * 1024 * 2);
  bf16* y0  = (bf16*)alloc((size_t)N * 896 * 2);
  bf16* y1  = (bf16*)alloc((size_t)N * 896 * 2);
  bf16* t0b = (bf16*)alloc((size_t)N * 896 * 2);
  bf16* t1b = (bf16*)alloc((size_t)N * 896 * 2);
  float* partA = (float*)alloc((size_t)2 * N * 1024 * 4);  // split-K partials
  float* partB = (float*)alloc((size_t)2 * N * 1024 * 4);

  // ---- input conversions (one launch: g0,g1,x0,x1) ------------------------
  {
    CvtB cb;
    cb.s[0] = g0; cb.d[0] = g0b; cb.n[0] = N * 4096;
    cb.s[1] = g1; cb.d[1] = g1b; cb.n[1] = N * 4096;
    cb.s[2] = x0; cb.d[2] = x0b; cb.n[2] = N * 1024;
    cb.s[3] = x1; cb.d[3] = x1b; cb.n[3] = N * 1280;
    cvt_batch<<<dim3(16384, 1, 4), 256, 0, stream>>>(cb);
  }

  // ---- 12 weight transposes in one launch ---------------------------------
  {
    TrBatch tb{};
    tb.nprob = 0; tb.blkStart[0] = 0;
    auto addTr = [&](const void* s, bf16* d, int R, int C, int P, int Q, int isb) {
      int i = tb.nprob++;
      tb.src[i] = s; tb.dst[i] = d;
      tb.R[i] = R; tb.C[i] = C; tb.Q[i] = Q; tb.isb[i] = isb;
      tb.nbx[i] = Q / 32;
      tb.blkStart[i + 1] = tb.blkStart[i] + (Q / 32) * (P / 32);
    };
    addTr(We1_0, BTe10, 1024, 819, 896, 1024, 0);
    addTr(We2_0, BTe20, 819, 819, 896, 896, 0);
    addTr(We1_1, BTe11, 1280, 1024, 1024, 1280, 0);
    addTr(We2_1, BTe21, 1024, 819, 896, 1024, 0);
    addTr(Wd1_0, BTd10, 819, 819, 896, 896, 0);
    addTr(Wd2_0, BTd20, 819, 1024, 1024, 896, 0);
    addTr(Wd1_1, BTd11, 819, 1024, 1024, 896, 0);
    addTr(Wd2_1, BTd21, 1024, 1280, 1280, 1024, 0);
    addTr(Ww0, BTw0, 819, 819, 896, 896, 0);
    addTr(Ww1, BTw1, 819, 819, 896, 896, 0);
    addTr(Wf0, BTf0, 819, 819, 896, 896, 0);
    addTr(Wf1, BTf1, 819, 819, 896, 896, 0);
    tr_batch<<<tb.blkStart[tb.nprob], 256, 0, stream>>>(tb);
  }

  BiasArgs ba;
  {
    const float* bsrc[8] = {be1_0, be2_0, be1_1, be2_1, bd1_0, bd2_0, bd1_1, bd2_1};
    float* bdst[8] = {pbe10, pbe20, pbe11, pbe21, pbd10, pbd20, pbd11, pbd21};
    int bn_[8] = {819, 819, 1024, 819, 819, 1024, 1024, 1280};
    int bnp[8] = {896, 896, 1024, 896, 896, 1024, 1024, 1280};
    for (int i = 0; i < 8; ++i) { ba.src[i] = bsrc[i]; ba.dst[i] = bdst[i]; ba.n[i] = bn_[i]; ba.np[i] = bnp[i]; }
  }
  biaspad<<<8, 256, 0, stream>>>(ba);

  // ---- batched GEMM helpers ----------------------------------------------
  GBatch gb{};
  int np = 0, maxN = 0;
  auto beg = [&]() { np = 0; maxN = 0; gb = GBatch{}; };
  auto add = [&](const bf16* A, const bf16* Bt, const float* bias,
                 float* Cf, int ldcf, bf16* Cb, int ldcb,
                 int K, int Npad, int Ntrue, int act) {
    gb.p[np].A = A; gb.p[np].Bt = Bt; gb.p[np].bias = bias;
    gb.p[np].Cf = Cf; gb.p[np].Cb = Cb; gb.p[np].Cp = nullptr;
    gb.p[np].K = K; gb.p[np].Npad = Npad;
    gb.p[np].ldcf = ldcf; gb.p[np].ldcb = ldcb;
    gb.p[np].Ntrue = Ntrue; gb.p[np].act = act;
    ++np;
    if (Npad > maxN) maxN = Npad;
  };
  auto addS = [&](const bf16* A, const bf16* Bt, float* Cp, int K, int Npad) {
    gb.p[np].A = A; gb.p[np].Bt = Bt; gb.p[np].bias = nullptr;
    gb.p[np].Cf = nullptr; gb.p[np].Cb = nullptr; gb.p[np].Cp = Cp;
    gb.p[np].K = K; gb.p[np].Npad = Npad;
    gb.p[np].ldcf = 0; gb.p[np].ldcb = 0; gb.p[np].Ntrue = 0; gb.p[np].act = 0;
    ++np;
    if (Npad > maxN) maxN = Npad;
  };
  auto goN = [&]() { gemm_nt_batch<1><<<dim3(maxN / 128, 32, np), 256, 0, stream>>>(gb); };
  auto goS = [&]() { gemm_nt_batch<2><<<dim3(maxN / 128, 32, np * 2), 256, 0, stream>>>(gb); };
  auto comb = [&](const float* bias0, float* Cf0, int ldf0, int Nt0, bf16* Cb0, int ldb0, int Np0, int act0,
                  const float* bias1, float* Cf1, int ldf1, int Nt1, bf16* Cb1, int ldb1, int Np1, int act1) {
    CBatch cb;
    cb.p[0] = {partA, bias0, Cf0, Cb0, Np0, ldf0, ldb0, Nt0, act0};
    cb.p[1] = {partB, bias1, Cf1, Cb1, Np1, ldf1, ldb1, Nt1, act1};
    combine_batch<<<dim3(4096, 1, 2), 256, 0, stream>>>(cb);
  };
  auto trb2 = [&](const bf16* s0, int C0, const bf16* s1, int C1) {
    TrBatch tb{};
    tb.nprob = 2; tb.blkStart[0] = 0;
    tb.src[0] = s0; tb.dst[0] = xT0; tb.R[0] = 4096; tb.C[0] = C0; tb.Q[0] = 4096;
    tb.isb[0] = 1; tb.nbx[0] = 128; tb.blkStart[1] = 128 * (C0 / 32);
    tb.src[1] = s1; tb.dst[1] = xT1; tb.R[1] = 4096; tb.C[1] = C1; tb.Q[1] = 4096;
    tb.isb[1] = 1; tb.nbx[1] = 128; tb.blkStart[2] = tb.blkStart[1] + 128 * (C1 / 32);
    tr_batch<<<tb.blkStart[2], 256, 0, stream>>>(tb);
  };

  // ---- encoders, reassociated: h1 = tanh(g@(x@We1)+b); h2 = tanh(g@(h1@We2)+b)
  beg();  // S1: w = x @ We1 (small K, no act)
  add(x0b, BTe10, nullptr, nullptr, 0, u0, 896, 1024, 896, 896, 0);
  add(x1b, BTe11, nullptr, nullptr, 0, u1, 1024, 1280, 1024, 1024, 0);
  goN();
  trb2(u0, 896, u1, 1024);                                   // w^T
  beg();  // S2: h1 = tanh(g @ w + be1)  [split-K, K=4096]
  addS(g0b, xT0, partA, 4096, 896);
  addS(g1b, xT1, partB, 4096, 1024);
  goS();
  comb(pbe10, nullptr, 0, 0, h0, 896, 896, 1,
       pbe11, nullptr, 0, 0, h1b, 1024, 1024, 1);
  beg();  // S3: s = h1 @ We2 (small K, no act)
  add(h0, BTe20, nullptr, nullptr, 0, u0, 896, 896, 896, 896, 0);
  add(h1b, BTe21, nullptr, nullptr, 0, u1, 896, 1024, 896, 896, 0);
  goN();
  trb2(u0, 896, u1, 896);                                    // s^T
  beg();  // S4: h2 = tanh(g @ s + be2)  [split-K] -> fp32
  addS(g0b, xT0, partA, 4096, 896);
  addS(g1b, xT1, partB, 4096, 896);
  goS();
  comb(pbe20, h20f, 896, 896, nullptr, 0, 896, 1,
       pbe21, h21f, 896, 896, nullptr, 0, 896, 1);

  // ---- z -----------------------------------------------------------------
  zkern<<<4096, 256, 0, stream>>>(h20f, h21f, we, out + OFF_Z, zb);

  // ---- four z-projections in one launch ----------------------------------
  beg();  // E: y0, y1 (act0), t0, t1 (act1)
  add(zb, BTw0, nullptr, nullptr, 0, y0, 896, 896, 896, 896, 0);
  add(zb, BTw1, nullptr, nullptr, 0, y1, 896, 896, 896, 896, 0);
  add(zb, BTf0, nullptr, nullptr, 0, t0b, 896, 896, 896, 896, 1);
  add(zb, BTf1, nullptr, nullptr, 0, t1b, 896, 896, 896, 896, 1);
  goN();
  beg();  // F: adj = sigmoid(y @ z^T)  (2048 blocks, kept separate)
  add(y0, zb, nullptr, out + OFF_ADJ0, 4096, nullptr, 0, 896, 4096, 4096, 2);
  add(y1, zb, nullptr, out + OFF_ADJ1, 4096, nullptr, 0, 896, 4096, 4096, 2);
  goN();

  // ---- feature decoders (0 || 1) -----------------------------------------
  trb2(t0b, 896, t1b, 896);                                  // t^T
  beg();  // G: r = g @ t  [split-K]
  addS(g0b, xT0, partA, 4096, 896);
  addS(g1b, xT1, partB, 4096, 896);
  goS();
  comb(nullptr, nullptr, 0, 0, u0, 896, 896, 0,
       nullptr, nullptr, 0, 0, u1, 896, 896, 0);
  beg();  // H: hr = tanh(r @ Wd1 + b)
  add(u0, BTd10, pbd10, nullptr, 0, h0, 896, 896, 896, 896, 1);
  add(u1, BTd11, pbd11, nullptr, 0, h1b, 1024, 896, 1024, 1024, 1);
  goN();
  trb2(h0, 896, h1b, 1024);                                  // hr^T
  beg();  // I: rin = g @ hr  [split-K]
  addS(g0b, xT0, partA, 4096, 896);
  addS(g1b, xT1, partB, 4096, 1024);
  goS();
  comb(nullptr, nullptr, 0, 0, u0, 896, 896, 0,
       nullptr, nullptr, 0, 0, u1, 1024, 1024, 0);
  beg();  // J: rec = tanh(rin @ Wd2 + b)  (fp32 out)
  add(u0, BTd20, pbd20, out + OFF_REC0, 1024, nullptr, 0, 896, 1024, 1024, 1);
  add(u1, BTd21, pbd21, out + OFF_REC1, 1280, nullptr, 0, 1024, 1280, 1280, 1);
  goN();

  // ---- q / p / cluster ---------------------------------------------------
  qkern<<<4096, 64, 0, stream>>>(out + OFF_Z, clus, out + OFF_Q);
  colsum_kern<<<5, 256, 0, stream>>>(out + OFF_Q, colsum);
  pkern<<<16, 256, 0, stream>>>(out + OFF_Q, colsum, out + OFF_P);
  hipMemcpyAsync(out + OFF_CL, (const void*)clus, 4095 * sizeof(float),
                 hipMemcpyDeviceToDevice, stream);
}

// Round 5
// 1109.015 us; speedup vs baseline: 1.1872x; 1.1473x over previous
//
#include <hip/hip_runtime.h>
#include <hip/hip_bf16.h>
#include <cstdint>
#include <cstddef>

typedef __bf16 bf16;
typedef __attribute__((ext_vector_type(8))) __bf16 bf16x8;
typedef __attribute__((ext_vector_type(4))) __bf16 bf16x4;
typedef __attribute__((ext_vector_type(4))) float f32x4;

// ---------------------------------------------------------------------------
// async global->LDS, 16B per lane (wave-uniform LDS base + lane*16)
__device__ __forceinline__ void gload_lds16(const void* g, void* l) {
  __builtin_amdgcn_global_load_lds(
      (const __attribute__((address_space(1))) uint32_t*)(uintptr_t)g,
      (__attribute__((address_space(3))) uint32_t*)(uintptr_t)l, 16, 0, 0);
}

__device__ __forceinline__ float actf(float v, int act) {
  if (act == 1) return tanhf(v);
  if (act == 2) return 1.f / (1.f + __expf(-v));
  return v;
}

// ---------------------------------------------------------------------------
// Batched NT GEMM, problems selected by decoded work-z.
// T1 XCD swizzle (m204 bijection): consecutive physical block ids round-robin
// across the 8 XCD L2s, so the 7-8 column-blocks sharing one A-row-tile (1 MB
// of g) each re-fetched it (FETCH 395 MB vs ~75 MB ideal, r3 counters). The
// bijection gives each XCD a contiguous x-inner chunk -> A-tile fetched once
// per XCD, reused from L2.
// SPLIT=2: split-K over 2 blocks; fp32 partials; combine finishes (residency:
// 448 blocks = 2.25/CU was grid-limited; 2x blocks -> 3.5+/CU).
// NOTE r4's transposed-output (Ct) epilogue was REVERTED: it caused a
// replay-dependent divergence (first run correct, warm re-runs diverged);
// transposes go through tr_batch again (proven race-free).
struct GProb {
  const bf16* A; const bf16* Bt; const float* bias;
  float* Cf; bf16* Cb; float* Cp;
  int K, Npad, ldcf, ldcb, Ntrue, act;
};
struct GBatch { GProb p[4]; };

template<int SPLIT>
__global__ __launch_bounds__(256, 2)
void gemm_nt_batch(GBatch b)
{
  // ---- T1: bijective XCD remap (x innermost in work order) ----
  const int nx = gridDim.x, ny = gridDim.y, nzz = gridDim.z;
  const int total = nx * ny * nzz;
  const int fid = (int)blockIdx.x + nx * ((int)blockIdx.y + ny * (int)blockIdx.z);
  const int q = total >> 3, r = total & 7;
  const int xcd = fid & 7, idx = fid >> 3;
  const int wid = (xcd < r ? xcd * (q + 1) : r * (q + 1) + (xcd - r) * q) + idx;
  const int wx = wid % nx;
  const int rest = wid / nx;
  const int wy = rest % ny;
  const int wz = rest / ny;

  const int prob = (SPLIT == 2) ? (wz >> 1) : wz;
  const int kz   = (SPLIT == 2) ? (wz & 1) : 0;
  const GProb P = b.p[prob];
  const long bn = (long)wx * 128;
  if (bn >= P.Npad) return;          // uniform whole-block exit (before any barrier)

  __shared__ __align__(16) bf16 As[128 * 32];
  __shared__ __align__(16) bf16 Bs[128 * 32];

  const int K    = P.K;
  const int tid  = threadIdx.x;
  const int lane = tid & 63, wave = tid >> 6;
  const int wr = wave >> 1, wc = wave & 1;
  const int l15 = lane & 15, quad = lane >> 4;
  const long bm = (long)wy * 128;

  // staging: slot = s*256 + tid; row=slot/4, chunk-slot=slot%4,
  // global chunk = cslot ^ (row&3) ^ ((row>>2)&3)  (involution; LDS slot
  // order == lane order as required by global_load_lds)
  long aoff[2], boff[2];
  int ldsoff[2];
#pragma unroll
  for (int s = 0; s < 2; ++s) {
    int slot = s * 256 + tid;
    int row = slot >> 2, cs = slot & 3;
    int gc = (cs ^ (row & 3) ^ ((row >> 2) & 3)) & 3;
    aoff[s] = (bm + row) * (long)K + gc * 8;
    boff[s] = (bn + row) * (long)K + gc * 8;
    ldsoff[s] = (s * 256 + wave * 64) * 8;   // wave-uniform base (elements)
  }

  // fragment reads: row r needs global chunk q at slot q^(r&3)^((r>>2)&3)
  const int cfr = ((quad ^ (lane & 3) ^ ((lane >> 2) & 3)) & 3) * 8;
  int afr[4], bfr[4];
#pragma unroll
  for (int i = 0; i < 4; ++i) {
    afr[i] = (wr * 64 + i * 16 + l15) * 32 + cfr;
    bfr[i] = (wc * 64 + i * 16 + l15) * 32 + cfr;
  }

  f32x4 acc[4][4];
#pragma unroll
  for (int i = 0; i < 4; ++i)
#pragma unroll
    for (int j = 0; j < 4; ++j) acc[i][j] = {0.f, 0.f, 0.f, 0.f};

  const int Kseg = K / SPLIT;
  const int kbeg = kz * Kseg;
  for (int k0 = kbeg; k0 < kbeg + Kseg; k0 += 32) {
    __syncthreads();                       // protect LDS from previous readers
    gload_lds16(P.A + aoff[0] + k0, As + ldsoff[0]);
    gload_lds16(P.A + aoff[1] + k0, As + ldsoff[1]);
    gload_lds16(P.Bt + boff[0] + k0, Bs + ldsoff[0]);
    gload_lds16(P.Bt + boff[1] + k0, Bs + ldsoff[1]);
    __syncthreads();                       // compiler drains vmcnt before barrier

    bf16x8 av[4], bv[4];
#pragma unroll
    for (int i = 0; i < 4; ++i) av[i] = *(const bf16x8*)(As + afr[i]);
#pragma unroll
    for (int j = 0; j < 4; ++j) bv[j] = *(const bf16x8*)(Bs + bfr[j]);
#pragma unroll
    for (int i = 0; i < 4; ++i)
#pragma unroll
      for (int j = 0; j < 4; ++j)
        acc[i][j] = __builtin_amdgcn_mfma_f32_16x16x32_bf16(av[i], bv[j], acc[i][j], 0, 0, 0);
  }

  // epilogue: C/D layout col=lane&15, row=quad*4+reg
  const long row0 = bm + wr * 64 + quad * 4;
  const long col0 = bn + wc * 64 + l15;
  if constexpr (SPLIT == 2) {
    float* Cp = P.Cp + (long)kz * 4096 * P.Npad;
#pragma unroll
    for (int i = 0; i < 4; ++i)
#pragma unroll
      for (int j = 0; j < 4; ++j)
#pragma unroll
        for (int t = 0; t < 4; ++t)
          Cp[(row0 + i * 16 + t) * (long)P.Npad + col0 + j * 16] = acc[i][j][t];
  } else {
    const int act = P.act;
#pragma unroll
    for (int i = 0; i < 4; ++i) {
#pragma unroll
      for (int j = 0; j < 4; ++j) {
        long c = col0 + j * 16;
        float bb = P.bias ? P.bias[c] : 0.f;
#pragma unroll
        for (int t = 0; t < 4; ++t) {
          long r = row0 + i * 16 + t;
          float v = actf(acc[i][j][t] + bb, act);
          if (P.Cf && c < P.Ntrue) P.Cf[r * P.ldcf + c] = v;
          if (P.Cb) P.Cb[r * P.ldcb + c] = (bf16)v;
        }
      }
    }
  }
}

// ---------------------------------------------------------------------------
// combine: out = act(part[0] + part[1] + bias); fp32 and/or bf16 stores.
struct CProb {
  const float* part; const float* bias;
  float* Cf; bf16* Cb;
  int Npad, ldcf, ldcb, Ntrue, act;
};
struct CBatch { CProb p[2]; };

__global__ void combine_batch(CBatch cb)
{
  const CProb P = cb.p[blockIdx.z];
  const int row = blockIdx.x;
  const int c4 = threadIdx.x * 4;
  if (c4 >= P.Npad) return;
  const long base = (long)row * P.Npad + c4;
  float4 a = *(const float4*)(P.part + base);
  float4 b = *(const float4*)(P.part + (long)4096 * P.Npad + base);
  float v[4] = {a.x + b.x, a.y + b.y, a.z + b.z, a.w + b.w};
  if (P.bias) {
    float4 bi = *(const float4*)(P.bias + c4);
    v[0] += bi.x; v[1] += bi.y; v[2] += bi.z; v[3] += bi.w;
  }
#pragma unroll
  for (int t = 0; t < 4; ++t) v[t] = actf(v[t], P.act);
  if (P.Cf && c4 < P.Ntrue) {
    float* o = P.Cf + (long)row * P.ldcf + c4;
    o[0] = v[0]; o[1] = v[1]; o[2] = v[2]; o[3] = v[3];
  }
  if (P.Cb) {
    bf16x4 o = {(bf16)v[0], (bf16)v[1], (bf16)v[2], (bf16)v[3]};
    *(bf16x4*)(P.Cb + (long)row * P.ldcb + c4) = o;
  }
}

// ---------------------------------------------------------------------------
// fused S4-combine + z: h2_i = tanh(partX0+partX1+be2_i); z = weighted merge.
// 224 threads x 4 cols = 896. Writes z fp32 [4096,819] + zb bf16 [4096,896].
__global__ void combz(const float* __restrict__ pA, const float* __restrict__ pB,
                      const float* __restrict__ bA, const float* __restrict__ bB,
                      const float* __restrict__ we, float* __restrict__ zout,
                      bf16* __restrict__ zb)
{
  const int n = blockIdx.x;
  const int c = threadIdx.x * 4;
  const long base = (long)n * 896 + c;
  const long half = (long)4096 * 896;
  float4 a0 = *(const float4*)(pA + base);
  float4 a1 = *(const float4*)(pA + half + base);
  float4 b0 = *(const float4*)(pB + base);
  float4 b1 = *(const float4*)(pB + half + base);
  float4 ba = *(const float4*)(bA + c);
  float4 bb = *(const float4*)(bB + c);
  const float w0 = we[n * 2], w1 = we[n * 2 + 1];
  const float inv = 1.f / (w0 + w1);
  float h0[4] = {a0.x + a1.x + ba.x, a0.y + a1.y + ba.y, a0.z + a1.z + ba.z, a0.w + a1.w + ba.w};
  float h1[4] = {b0.x + b1.x + bb.x, b0.y + b1.y + bb.y, b0.z + b1.z + bb.z, b0.w + b1.w + bb.w};
  bf16x4 o;
#pragma unroll
  for (int t = 0; t < 4; ++t) {
    float v = (w0 * tanhf(h0[t]) + w1 * tanhf(h1[t])) * inv;
    o[t] = (bf16)v;
    if (c + t < 819) zout[(long)n * 819 + c + t] = v;
  }
  *(bf16x4*)(zb + base) = o;
}

// ---------------------------------------------------------------------------
// Batched padded transpose: dst[P x Q] = src^T zero-padded.
struct TrBatch {
  const void* src[14]; bf16* dst[14];
  int R[14], C[14], Q[14], nbx[14], isb[14];
  int blkStart[15];
  int nprob;
};

__global__ void tr_batch(TrBatch a)
{
  __shared__ float tile[32][33];
  int pi = 0, b = blockIdx.x;
  while (b >= a.blkStart[pi + 1]) ++pi;
  const int rel = b - a.blkStart[pi];
  const int nbx = a.nbx[pi];
  const int q0 = (rel % nbx) * 32;       // src-row block
  const int p0 = (rel / nbx) * 32;       // src-col block
  const int R = a.R[pi], C = a.C[pi], Q = a.Q[pi];
  const bool isb = a.isb[pi] != 0;
  const void* src = a.src[pi];
  const int tx = threadIdx.x & 31, ty = threadIdx.x >> 5;
#pragma unroll
  for (int y = ty; y < 32; y += 8) {
    int r = q0 + y, c = p0 + tx;
    float v = 0.f;
    if (r < R && c < C)
      v = isb ? (float)((const bf16*)src)[(long)r * C + c]
              : ((const float*)src)[(long)r * C + c];
    tile[y][tx] = v;
  }
  __syncthreads();
  bf16* dst = a.dst[pi];
#pragma unroll
  for (int y = ty; y < 32; y += 8)
    dst[(long)(p0 + y) * Q + (q0 + tx)] = (bf16)tile[tx][y];
}

// fp32 -> bf16, 4 buffers per launch (blockIdx.z), n % 4 == 0
struct CvtB { const float* s[4]; bf16* d[4]; long n[4]; };
__global__ void cvt_batch(CvtB cb)
{
  const float* s = cb.s[blockIdx.z];
  bf16* d = cb.d[blockIdx.z];
  long i = ((long)blockIdx.x * blockDim.x + threadIdx.x) * 4;
  if (i >= cb.n[blockIdx.z]) return;
  float4 v = *(const float4*)(s + i);
  bf16x4 o = {(bf16)v.x, (bf16)v.y, (bf16)v.z, (bf16)v.w};
  *(bf16x4*)(d + i) = o;
}

// Student-t q per row (one wave per row). NO atomics — colsum done separately.
__global__ void qkern(const float* __restrict__ z, const float* __restrict__ cl,
                      float* __restrict__ qout)
{
  const int n = blockIdx.x;
  const int lane = threadIdx.x;
  float d0 = 0, d1 = 0, d2 = 0, d3 = 0, d4 = 0;
  for (int s = lane; s < 819; s += 64) {
    float zv = z[(long)n * 819 + s];
    float t0 = zv - cl[0 * 819 + s]; d0 += t0 * t0;
    float t1 = zv - cl[1 * 819 + s]; d1 += t1 * t1;
    float t2 = zv - cl[2 * 819 + s]; d2 += t2 * t2;
    float t3 = zv - cl[3 * 819 + s]; d3 += t3 * t3;
    float t4 = zv - cl[4 * 819 + s]; d4 += t4 * t4;
  }
#pragma unroll
  for (int off = 32; off > 0; off >>= 1) {
    d0 += __shfl_xor(d0, off);
    d1 += __shfl_xor(d1, off);
    d2 += __shfl_xor(d2, off);
    d3 += __shfl_xor(d3, off);
    d4 += __shfl_xor(d4, off);
  }
  if (lane == 0) {
    float q0 = 1.f / (1.f + d0), q1 = 1.f / (1.f + d1), q2 = 1.f / (1.f + d2);
    float q3 = 1.f / (1.f + d3), q4 = 1.f / (1.f + d4);
    float inv = 1.f / (q0 + q1 + q2 + q3 + q4);
    float* qr = qout + (long)n * 5;
    qr[0] = q0 * inv; qr[1] = q1 * inv; qr[2] = q2 * inv;
    qr[3] = q3 * inv; qr[4] = q4 * inv;
  }
}

__global__ void colsum_kern(const float* __restrict__ q, float* __restrict__ colsum)
{
  __shared__ float red[256];
  const int k = blockIdx.x;
  float s = 0.f;
  for (int n = threadIdx.x; n < 4096; n += 256) s += q[(long)n * 5 + k];
  red[threadIdx.x] = s;
  __syncthreads();
  for (int w = 128; w > 0; w >>= 1) {
    if (threadIdx.x < w) red[threadIdx.x] += red[threadIdx.x + w];
    __syncthreads();
  }
  if (threadIdx.x == 0) colsum[k] = red[0];
}

__global__ void pkern(const float* __restrict__ q, const float* __restrict__ colsum,
                      float* __restrict__ p)
{
  int n = blockIdx.x * blockDim.x + threadIdx.x;
  if (n >= 4096) return;
  float w[5], s = 0.f;
#pragma unroll
  for (int k = 0; k < 5; ++k) {
    float qv = q[(long)n * 5 + k];
    w[k] = qv * qv / colsum[k];
    s += w[k];
  }
  float inv = 1.f / s;
#pragma unroll
  for (int k = 0; k < 5; ++k) p[(long)n * 5 + k] = w[k] * inv;
}

struct BiasArgs {
  const float* src[8];
  float* dst[8];
  int n[8];
  int np[8];
};

__global__ void biaspad(BiasArgs a)
{
  int b = blockIdx.x;
  for (int i = threadIdx.x; i < a.np[b]; i += blockDim.x)
    a.dst[b][i] = (i < a.n[b]) ? a.src[b][i] : 0.f;
}

// ---------------------------------------------------------------------------
extern "C" void kernel_launch(void* const* d_in, const int* in_sizes, int n_in,
                              void* d_out, int out_size, void* d_ws, size_t ws_size,
                              hipStream_t stream)
{
  (void)in_sizes; (void)n_in; (void)out_size; (void)ws_size;
  const float* x0    = (const float*)d_in[0];
  const float* x1    = (const float*)d_in[1];
  const float* we    = (const float*)d_in[2];
  const float* g0    = (const float*)d_in[3];
  const float* g1    = (const float*)d_in[4];
  const float* We1_0 = (const float*)d_in[5];
  const float* be1_0 = (const float*)d_in[6];
  const float* We2_0 = (const float*)d_in[7];
  const float* be2_0 = (const float*)d_in[8];
  const float* We1_1 = (const float*)d_in[9];
  const float* be1_1 = (const float*)d_in[10];
  const float* We2_1 = (const float*)d_in[11];
  const float* be2_1 = (const float*)d_in[12];
  const float* Wd1_0 = (const float*)d_in[13];
  const float* bd1_0 = (const float*)d_in[14];
  const float* Wd2_0 = (const float*)d_in[15];
  const float* bd2_0 = (const float*)d_in[16];
  const float* Wd1_1 = (const float*)d_in[17];
  const float* bd1_1 = (const float*)d_in[18];
  const float* Wd2_1 = (const float*)d_in[19];
  const float* bd2_1 = (const float*)d_in[20];
  const float* Ww0   = (const float*)d_in[21];
  const float* Ww1   = (const float*)d_in[22];
  const float* Wf0   = (const float*)d_in[23];
  const float* Wf1   = (const float*)d_in[24];
  const float* clus  = (const float*)d_in[25];
  float* out = (float*)d_out;

  const size_t OFF_REC0 = 0;
  const size_t OFF_REC1 = 4194304;
  const size_t OFF_ADJ0 = 9437184;
  const size_t OFF_ADJ1 = 26214400;
  const size_t OFF_Z    = 42991616;
  const size_t OFF_P    = 46346240;
  const size_t OFF_Q    = 46366720;
  const size_t OFF_CL   = 46387200;

  char* ws = (char*)d_ws;
  size_t off = 0;
  auto alloc = [&](size_t bytes) -> void* {
    off = (off + 255) & ~(size_t)255;
    void* p = ws + off;
    off += bytes;
    return p;
  };
  const long N = 4096;
  bf16* g0b   = (bf16*)alloc((size_t)N * 4096 * 2);
  bf16* g1b   = (bf16*)alloc((size_t)N * 4096 * 2);
  bf16* x0b   = (bf16*)alloc((size_t)N * 1024 * 2);
  bf16* x1b   = (bf16*)alloc((size_t)N * 1280 * 2);
  bf16* BTe10 = (bf16*)alloc((size_t)896 * 1024 * 2);
  bf16* BTe20 = (bf16*)alloc((size_t)896 * 896 * 2);
  bf16* BTe11 = (bf16*)alloc((size_t)1024 * 1280 * 2);
  bf16* BTe21 = (bf16*)alloc((size_t)896 * 1024 * 2);
  bf16* BTd10 = (bf16*)alloc((size_t)896 * 896 * 2);
  bf16* BTd20 = (bf16*)alloc((size_t)1024 * 896 * 2);
  bf16* BTd11 = (bf16*)alloc((size_t)1024 * 896 * 2);
  bf16* BTd21 = (bf16*)alloc((size_t)1280 * 1024 * 2);
  bf16* BTw0  = (bf16*)alloc((size_t)896 * 896 * 2);
  bf16* BTw1  = (bf16*)alloc((size_t)896 * 896 * 2);
  bf16* BTf0  = (bf16*)alloc((size_t)896 * 896 * 2);
  bf16* BTf1  = (bf16*)alloc((size_t)896 * 896 * 2);
  float* pbe10 = (float*)alloc(896 * 4);
  float* pbe20 = (float*)alloc(896 * 4);
  float* pbe11 = (float*)alloc(1024 * 4);
  float* pbe21 = (float*)alloc(896 * 4);
  float* pbd10 = (float*)alloc(896 * 4);
  float* pbd20 = (float*)alloc(1024 * 4);
  float* pbd11 = (float*)alloc(1024 * 4);
  float* pbd21 = (float*)alloc(1280 * 4);
  bf16* zb     = (bf16*)alloc((size_t)N * 896 * 2);
  float* colsum = (float*)alloc(64);
  bf16* xT0 = (bf16*)alloc((size_t)1024 * 4096 * 2);  // transposed operands, ch 0
  bf16* xT1 = (bf16*)alloc((size_t)1280 * 4096 * 2);  // transposed operands, ch 1
  bf16* u0  = (bf16*)alloc((size_t)N * 1024 * 2);
  bf16* u1  = (bf16*)alloc((size_t)N * 1280 * 2);
  bf16* h0  = (bf16*)alloc((size_t)N * 896 * 2);
  bf16* h1b = (bf16*)alloc((size_t)N * 1024 * 2);
  bf16* y0  = (bf16*)alloc((size_t)N * 896 * 2);
  bf16* y1  = (bf16*)alloc((size_t)N * 896 * 2);
  bf16* t0b = (bf16*)alloc((size_t)N * 896 * 2);
  bf16* t1b = (bf16*)alloc((size_t)N * 896 * 2);
  float* partA = (float*)alloc((size_t)2 * N * 1024 * 4);  // split-K partials
  float* partB = (float*)alloc((size_t)2 * N * 1024 * 4);

  // ---- input conversions (one launch: g0,g1,x0,x1) ------------------------
  {
    CvtB cb;
    cb.s[0] = g0; cb.d[0] = g0b; cb.n[0] = N * 4096;
    cb.s[1] = g1; cb.d[1] = g1b; cb.n[1] = N * 4096;
    cb.s[2] = x0; cb.d[2] = x0b; cb.n[2] = N * 1024;
    cb.s[3] = x1; cb.d[3] = x1b; cb.n[3] = N * 1280;
    cvt_batch<<<dim3(16384, 1, 4), 256, 0, stream>>>(cb);
  }

  // ---- 12 weight transposes in one launch ---------------------------------
  {
    TrBatch tb{};
    tb.nprob = 0; tb.blkStart[0] = 0;
    auto addTr = [&](const void* s, bf16* d, int R, int C, int P, int Q, int isb) {
      int i = tb.nprob++;
      tb.src[i] = s; tb.dst[i] = d;
      tb.R[i] = R; tb.C[i] = C; tb.Q[i] = Q; tb.isb[i] = isb;
      tb.nbx[i] = Q / 32;
      tb.blkStart[i + 1] = tb.blkStart[i] + (Q / 32) * (P / 32);
    };
    addTr(We1_0, BTe10, 1024, 819, 896, 1024, 0);
    addTr(We2_0, BTe20, 819, 819, 896, 896, 0);
    addTr(We1_1, BTe11, 1280, 1024, 1024, 1280, 0);
    addTr(We2_1, BTe21, 1024, 819, 896, 1024, 0);
    addTr(Wd1_0, BTd10, 819, 819, 896, 896, 0);
    addTr(Wd2_0, BTd20, 819, 1024, 1024, 896, 0);
    addTr(Wd1_1, BTd11, 819, 1024, 1024, 896, 0);
    addTr(Wd2_1, BTd21, 1024, 1280, 1280, 1024, 0);
    addTr(Ww0, BTw0, 819, 819, 896, 896, 0);
    addTr(Ww1, BTw1, 819, 819, 896, 896, 0);
    addTr(Wf0, BTf0, 819, 819, 896, 896, 0);
    addTr(Wf1, BTf1, 819, 819, 896, 896, 0);
    tr_batch<<<tb.blkStart[tb.nprob], 256, 0, stream>>>(tb);
  }

  BiasArgs ba;
  {
    const float* bsrc[8] = {be1_0, be2_0, be1_1, be2_1, bd1_0, bd2_0, bd1_1, bd2_1};
    float* bdst[8] = {pbe10, pbe20, pbe11, pbe21, pbd10, pbd20, pbd11, pbd21};
    int bn_[8] = {819, 819, 1024, 819, 819, 1024, 1024, 1280};
    int bnp[8] = {896, 896, 1024, 896, 896, 1024, 1024, 1280};
    for (int i = 0; i < 8; ++i) { ba.src[i] = bsrc[i]; ba.dst[i] = bdst[i]; ba.n[i] = bn_[i]; ba.np[i] = bnp[i]; }
  }
  biaspad<<<8, 256, 0, stream>>>(ba);

  // ---- batched GEMM helpers ----------------------------------------------
  GBatch gb{};
  int np = 0, maxN = 0;
  auto beg = [&]() { np = 0; maxN = 0; gb = GBatch{}; };
  auto add = [&](const bf16* A, const bf16* Bt, const float* bias,
                 float* Cf, int ldcf, bf16* Cb, int ldcb,
                 int K, int Npad, int Ntrue, int act) {
    gb.p[np].A = A; gb.p[np].Bt = Bt; gb.p[np].bias = bias;
    gb.p[np].Cf = Cf; gb.p[np].Cb = Cb; gb.p[np].Cp = nullptr;
    gb.p[np].K = K; gb.p[np].Npad = Npad;
    gb.p[np].ldcf = ldcf; gb.p[np].ldcb = ldcb;
    gb.p[np].Ntrue = Ntrue; gb.p[np].act = act;
    ++np;
    if (Npad > maxN) maxN = Npad;
  };
  auto addS = [&](const bf16* A, const bf16* Bt, float* Cp, int K, int Npad) {
    gb.p[np].A = A; gb.p[np].Bt = Bt; gb.p[np].bias = nullptr;
    gb.p[np].Cf = nullptr; gb.p[np].Cb = nullptr; gb.p[np].Cp = Cp;
    gb.p[np].K = K; gb.p[np].Npad = Npad;
    gb.p[np].ldcf = 0; gb.p[np].ldcb = 0; gb.p[np].Ntrue = 0; gb.p[np].act = 0;
    ++np;
    if (Npad > maxN) maxN = Npad;
  };
  auto goN = [&]() { gemm_nt_batch<1><<<dim3(maxN / 128, 32, np), 256, 0, stream>>>(gb); };
  auto goS = [&]() { gemm_nt_batch<2><<<dim3(maxN / 128, 32, np * 2), 256, 0, stream>>>(gb); };
  auto comb = [&](const float* bias0, float* Cf0, int ldf0, int Nt0, bf16* Cb0, int ldb0, int Np0, int act0,
                  const float* bias1, float* Cf1, int ldf1, int Nt1, bf16* Cb1, int ldb1, int Np1, int act1) {
    CBatch cb;
    cb.p[0] = {partA, bias0, Cf0, Cb0, Np0, ldf0, ldb0, Nt0, act0};
    cb.p[1] = {partB, bias1, Cf1, Cb1, Np1, ldf1, ldb1, Nt1, act1};
    combine_batch<<<dim3(4096, 1, 2), 256, 0, stream>>>(cb);
  };
  auto trb2 = [&](const bf16* s0, int C0, const bf16* s1, int C1) {
    TrBatch tb{};
    tb.nprob = 2; tb.blkStart[0] = 0;
    tb.src[0] = s0; tb.dst[0] = xT0; tb.R[0] = 4096; tb.C[0] = C0; tb.Q[0] = 4096;
    tb.isb[0] = 1; tb.nbx[0] = 128; tb.blkStart[1] = 128 * (C0 / 32);
    tb.src[1] = s1; tb.dst[1] = xT1; tb.R[1] = 4096; tb.C[1] = C1; tb.Q[1] = 4096;
    tb.isb[1] = 1; tb.nbx[1] = 128; tb.blkStart[2] = tb.blkStart[1] + 128 * (C1 / 32);
    tr_batch<<<tb.blkStart[2], 256, 0, stream>>>(tb);
  };

  // ---- encoders, reassociated: h1 = tanh(g@(x@We1)+b); h2 = tanh(g@(h1@We2)+b)
  beg();  // S1: w = x @ We1 (small K, no act)
  add(x0b, BTe10, nullptr, nullptr, 0, u0, 896, 1024, 896, 896, 0);
  add(x1b, BTe11, nullptr, nullptr, 0, u1, 1024, 1280, 1024, 1024, 0);
  goN();
  trb2(u0, 896, u1, 1024);                                   // w^T
  beg();  // S2: h1 = tanh(g @ w + be1)  [split-K, K=4096]
  addS(g0b, xT0, partA, 4096, 896);
  addS(g1b, xT1, partB, 4096, 1024);
  goS();
  comb(pbe10, nullptr, 0, 0, h0, 896, 896, 1,
       pbe11, nullptr, 0, 0, h1b, 1024, 1024, 1);
  beg();  // S3: s = h1 @ We2 (small K, no act)
  add(h0, BTe20, nullptr, nullptr, 0, u0, 896, 896, 896, 896, 0);
  add(h1b, BTe21, nullptr, nullptr, 0, u1, 896, 1024, 896, 896, 0);
  goN();
  trb2(u0, 896, u1, 896);                                    // s^T
  beg();  // S4: h2 = tanh(g @ s + be2)  [split-K] -> fused combine + z
  addS(g0b, xT0, partA, 4096, 896);
  addS(g1b, xT1, partB, 4096, 896);
  goS();
  combz<<<4096, 224, 0, stream>>>(partA, partB, pbe20, pbe21, we, out + OFF_Z, zb);

  // ---- four z-projections in one launch ----------------------------------
  beg();  // E: y0, y1 (act0), t0, t1 (act1)
  add(zb, BTw0, nullptr, nullptr, 0, y0, 896, 896, 896, 896, 0);
  add(zb, BTw1, nullptr, nullptr, 0, y1, 896, 896, 896, 896, 0);
  add(zb, BTf0, nullptr, nullptr, 0, t0b, 896, 896, 896, 896, 1);
  add(zb, BTf1, nullptr, nullptr, 0, t1b, 896, 896, 896, 896, 1);
  goN();
  beg();  // F: adj = sigmoid(y @ z^T)
  add(y0, zb, nullptr, out + OFF_ADJ0, 4096, nullptr, 0, 896, 4096, 4096, 2);
  add(y1, zb, nullptr, out + OFF_ADJ1, 4096, nullptr, 0, 896, 4096, 4096, 2);
  goN();

  // ---- feature decoders (0 || 1) -----------------------------------------
  trb2(t0b, 896, t1b, 896);                                  // t^T
  beg();  // G: r = g @ t  [split-K]
  addS(g0b, xT0, partA, 4096, 896);
  addS(g1b, xT1, partB, 4096, 896);
  goS();
  comb(nullptr, nullptr, 0, 0, u0, 896, 896, 0,
       nullptr, nullptr, 0, 0, u1, 896, 896, 0);
  beg();  // H: hr = tanh(r @ Wd1 + b)
  add(u0, BTd10, pbd10, nullptr, 0, h0, 896, 896, 896, 896, 1);
  add(u1, BTd11, pbd11, nullptr, 0, h1b, 1024, 896, 1024, 1024, 1);
  goN();
  trb2(h0, 896, h1b, 1024);                                  // hr^T
  beg();  // I: rin = g @ hr  [split-K]
  addS(g0b, xT0, partA, 4096, 896);
  addS(g1b, xT1, partB, 4096, 1024);
  goS();
  comb(nullptr, nullptr, 0, 0, u0, 896, 896, 0,
       nullptr, nullptr, 0, 0, u1, 1024, 1024, 0);
  beg();  // J: rec = tanh(rin @ Wd2 + b)  (fp32 out)
  add(u0, BTd20, pbd20, out + OFF_REC0, 1024, nullptr, 0, 896, 1024, 1024, 1);
  add(u1, BTd21, pbd21, out + OFF_REC1, 1280, nullptr, 0, 1024, 1280, 1280, 1);
  goN();

  // ---- q / p / cluster ---------------------------------------------------
  qkern<<<4096, 64, 0, stream>>>(out + OFF_Z, clus, out + OFF_Q);
  colsum_kern<<<5, 256, 0, stream>>>(out + OFF_Q, colsum);
  pkern<<<16, 256, 0, stream>>>(out + OFF_Q, colsum, out + OFF_P);
  hipMemcpyAsync(out + OFF_CL, (const void*)clus, 4095 * sizeof(float),
                 hipMemcpyDeviceToDevice, stream);
}

// Round 6
// 1072.144 us; speedup vs baseline: 1.2280x; 1.0344x over previous
//
#include <hip/hip_runtime.h>
#include <hip/hip_bf16.h>
#include <cstdint>
#include <cstddef>

typedef __bf16 bf16;
typedef __attribute__((ext_vector_type(8))) __bf16 bf16x8;
typedef __attribute__((ext_vector_type(4))) __bf16 bf16x4;
typedef __attribute__((ext_vector_type(4))) float f32x4;

// ---------------------------------------------------------------------------
// async global->LDS, 16B per lane (wave-uniform LDS base + lane*16)
__device__ __forceinline__ void gload_lds16(const void* g, void* l) {
  __builtin_amdgcn_global_load_lds(
      (const __attribute__((address_space(1))) uint32_t*)(uintptr_t)g,
      (__attribute__((address_space(3))) uint32_t*)(uintptr_t)l, 16, 0, 0);
}

__device__ __forceinline__ float actf(float v, int act) {
  if (act == 1) return tanhf(v);
  if (act == 2) return 1.f / (1.f + __expf(-v));
  return v;
}

// ---------------------------------------------------------------------------
// Batched NT GEMM, problems selected by decoded work-z.
// T1 XCD swizzle (m204 bijection): verified r5 — split-K FETCH 395->65 MB.
// SPLIT=2: split-K over 2 blocks; fp32 partials; combine finishes.
// BK=64 (r6): the 2-barrier K-loop pays a full vmcnt(0) drain per K-step;
// at BK=32 that is 28-64 drains per block with only 16 MFMA/wave between.
// BK=64 halves the drain count (32 MFMA/wave per barrier-pair), LDS 32KB
// (>=5 blocks/CU cap, above the ~3.75 grid limit; avoids m132's BK=128
// 64KB occupancy cliff). Inner loop = two sequential {load,16xMFMA} groups
// so only 8 fragments live (VGPR stays ~60-75).
// XOR swizzle now over 8 chunks: gc = cs ^ (row&7) (involution, both sides);
// ds_read_b128 banks = cslot*4+{0..3}, cslot a permutation of 0..7 per
// 8 lanes -> 2 lanes/bank = free (m136).
struct GProb {
  const bf16* A; const bf16* Bt; const float* bias;
  float* Cf; bf16* Cb; float* Cp;
  int K, Npad, ldcf, ldcb, Ntrue, act;
};
struct GBatch { GProb p[4]; };

template<int SPLIT>
__global__ __launch_bounds__(256, 2)
void gemm_nt_batch(GBatch b)
{
  // ---- T1: bijective XCD remap (x innermost in work order) ----
  const int nx = gridDim.x, ny = gridDim.y, nzz = gridDim.z;
  const int total = nx * ny * nzz;
  const int fid = (int)blockIdx.x + nx * ((int)blockIdx.y + ny * (int)blockIdx.z);
  const int q = total >> 3, r = total & 7;
  const int xcd = fid & 7, idx = fid >> 3;
  const int wid = (xcd < r ? xcd * (q + 1) : r * (q + 1) + (xcd - r) * q) + idx;
  const int wx = wid % nx;
  const int rest = wid / nx;
  const int wy = rest % ny;
  const int wz = rest / ny;

  const int prob = (SPLIT == 2) ? (wz >> 1) : wz;
  const int kz   = (SPLIT == 2) ? (wz & 1) : 0;
  const GProb P = b.p[prob];
  const long bn = (long)wx * 128;
  if (bn >= P.Npad) return;          // uniform whole-block exit (before any barrier)

  __shared__ __align__(16) bf16 As[128 * 64];
  __shared__ __align__(16) bf16 Bs[128 * 64];

  const int K    = P.K;
  const int tid  = threadIdx.x;
  const int lane = tid & 63, wave = tid >> 6;
  const int wr = wave >> 1, wc = wave & 1;
  const int l15 = lane & 15, quad = lane >> 4;
  const long bm = (long)wy * 128;

  // staging: slot = s*256 + tid; row = slot/8, chunk-slot = slot%8,
  // global chunk = cslot ^ (row&7)  (involution; LDS slot order == lane
  // order as required by global_load_lds: dest = wave-uniform base + lane*16)
  long aoff[4], boff[4];
  int ldsoff[4];
#pragma unroll
  for (int s = 0; s < 4; ++s) {
    int slot = s * 256 + tid;
    int row = slot >> 3, cs = slot & 7;
    int gc = cs ^ (row & 7);
    aoff[s] = (bm + row) * (long)K + gc * 8;
    boff[s] = (bn + row) * (long)K + gc * 8;
    ldsoff[s] = (s * 256 + wave * 64) * 8;   // wave-uniform base (elements)
  }

  // fragment reads: MFMA k-slice ks (k = ks*32 + quad*8) wants global chunk
  // ks*4+quad of row r at slot (ks*4+quad)^(r&7); r&7 == l15&7 here.
  const int cfr0 = ((0 * 4 + quad) ^ (l15 & 7)) * 8;
  const int cfr1 = ((1 * 4 + quad) ^ (l15 & 7)) * 8;
  int afr[2][4], bfr[2][4];
#pragma unroll
  for (int i = 0; i < 4; ++i) {
    afr[0][i] = (wr * 64 + i * 16 + l15) * 64 + cfr0;
    afr[1][i] = (wr * 64 + i * 16 + l15) * 64 + cfr1;
    bfr[0][i] = (wc * 64 + i * 16 + l15) * 64 + cfr0;
    bfr[1][i] = (wc * 64 + i * 16 + l15) * 64 + cfr1;
  }

  f32x4 acc[4][4];
#pragma unroll
  for (int i = 0; i < 4; ++i)
#pragma unroll
    for (int j = 0; j < 4; ++j) acc[i][j] = {0.f, 0.f, 0.f, 0.f};

  const int Kseg = K / SPLIT;
  const int kbeg = kz * Kseg;
  for (int k0 = kbeg; k0 < kbeg + Kseg; k0 += 64) {
    __syncthreads();                       // protect LDS from previous readers
#pragma unroll
    for (int s = 0; s < 4; ++s) {
      gload_lds16(P.A + aoff[s] + k0, As + ldsoff[s]);
      gload_lds16(P.Bt + boff[s] + k0, Bs + ldsoff[s]);
    }
    __syncthreads();                       // compiler drains vmcnt before barrier

    // two sequential k-slice groups: only 8 fragments live at a time
#pragma unroll
    for (int ks = 0; ks < 2; ++ks) {
      bf16x8 av[4], bv[4];
#pragma unroll
      for (int i = 0; i < 4; ++i) av[i] = *(const bf16x8*)(As + afr[ks][i]);
#pragma unroll
      for (int j = 0; j < 4; ++j) bv[j] = *(const bf16x8*)(Bs + bfr[ks][j]);
#pragma unroll
      for (int i = 0; i < 4; ++i)
#pragma unroll
        for (int j = 0; j < 4; ++j)
          acc[i][j] = __builtin_amdgcn_mfma_f32_16x16x32_bf16(av[i], bv[j], acc[i][j], 0, 0, 0);
    }
  }

  // epilogue: C/D layout col=lane&15, row=quad*4+reg
  const long row0 = bm + wr * 64 + quad * 4;
  const long col0 = bn + wc * 64 + l15;
  if constexpr (SPLIT == 2) {
    float* Cp = P.Cp + (long)kz * 4096 * P.Npad;
#pragma unroll
    for (int i = 0; i < 4; ++i)
#pragma unroll
      for (int j = 0; j < 4; ++j)
#pragma unroll
        for (int t = 0; t < 4; ++t)
          Cp[(row0 + i * 16 + t) * (long)P.Npad + col0 + j * 16] = acc[i][j][t];
  } else {
    const int act = P.act;
#pragma unroll
    for (int i = 0; i < 4; ++i) {
#pragma unroll
      for (int j = 0; j < 4; ++j) {
        long c = col0 + j * 16;
        float bb = P.bias ? P.bias[c] : 0.f;
#pragma unroll
        for (int t = 0; t < 4; ++t) {
          long r = row0 + i * 16 + t;
          float v = actf(acc[i][j][t] + bb, act);
          if (P.Cf && c < P.Ntrue) P.Cf[r * P.ldcf + c] = v;
          if (P.Cb) P.Cb[r * P.ldcb + c] = (bf16)v;
        }
      }
    }
  }
}

// ---------------------------------------------------------------------------
// combine: out = act(part[0] + part[1] + bias); fp32 and/or bf16 stores.
struct CProb {
  const float* part; const float* bias;
  float* Cf; bf16* Cb;
  int Npad, ldcf, ldcb, Ntrue, act;
};
struct CBatch { CProb p[2]; };

__global__ void combine_batch(CBatch cb)
{
  const CProb P = cb.p[blockIdx.z];
  const int row = blockIdx.x;
  const int c4 = threadIdx.x * 4;
  if (c4 >= P.Npad) return;
  const long base = (long)row * P.Npad + c4;
  float4 a = *(const float4*)(P.part + base);
  float4 b = *(const float4*)(P.part + (long)4096 * P.Npad + base);
  float v[4] = {a.x + b.x, a.y + b.y, a.z + b.z, a.w + b.w};
  if (P.bias) {
    float4 bi = *(const float4*)(P.bias + c4);
    v[0] += bi.x; v[1] += bi.y; v[2] += bi.z; v[3] += bi.w;
  }
#pragma unroll
  for (int t = 0; t < 4; ++t) v[t] = actf(v[t], P.act);
  if (P.Cf && c4 < P.Ntrue) {
    float* o = P.Cf + (long)row * P.ldcf + c4;
    o[0] = v[0]; o[1] = v[1]; o[2] = v[2]; o[3] = v[3];
  }
  if (P.Cb) {
    bf16x4 o = {(bf16)v[0], (bf16)v[1], (bf16)v[2], (bf16)v[3]};
    *(bf16x4*)(P.Cb + (long)row * P.ldcb + c4) = o;
  }
}

// ---------------------------------------------------------------------------
// fused S4-combine + z: h2_i = tanh(partX0+partX1+be2_i); z = weighted merge.
// 224 threads x 4 cols = 896. Writes z fp32 [4096,819] + zb bf16 [4096,896].
__global__ void combz(const float* __restrict__ pA, const float* __restrict__ pB,
                      const float* __restrict__ bA, const float* __restrict__ bB,
                      const float* __restrict__ we, float* __restrict__ zout,
                      bf16* __restrict__ zb)
{
  const int n = blockIdx.x;
  const int c = threadIdx.x * 4;
  const long base = (long)n * 896 + c;
  const long half = (long)4096 * 896;
  float4 a0 = *(const float4*)(pA + base);
  float4 a1 = *(const float4*)(pA + half + base);
  float4 b0 = *(const float4*)(pB + base);
  float4 b1 = *(const float4*)(pB + half + base);
  float4 ba = *(const float4*)(bA + c);
  float4 bb = *(const float4*)(bB + c);
  const float w0 = we[n * 2], w1 = we[n * 2 + 1];
  const float inv = 1.f / (w0 + w1);
  float h0[4] = {a0.x + a1.x + ba.x, a0.y + a1.y + ba.y, a0.z + a1.z + ba.z, a0.w + a1.w + ba.w};
  float h1[4] = {b0.x + b1.x + bb.x, b0.y + b1.y + bb.y, b0.z + b1.z + bb.z, b0.w + b1.w + bb.w};
  bf16x4 o;
#pragma unroll
  for (int t = 0; t < 4; ++t) {
    float v = (w0 * tanhf(h0[t]) + w1 * tanhf(h1[t])) * inv;
    o[t] = (bf16)v;
    if (c + t < 819) zout[(long)n * 819 + c + t] = v;
  }
  *(bf16x4*)(zb + base) = o;
}

// ---------------------------------------------------------------------------
// Batched padded transpose: dst[P x Q] = src^T zero-padded.
struct TrBatch {
  const void* src[14]; bf16* dst[14];
  int R[14], C[14], Q[14], nbx[14], isb[14];
  int blkStart[15];
  int nprob;
};

__global__ void tr_batch(TrBatch a)
{
  __shared__ float tile[32][33];
  int pi = 0, b = blockIdx.x;
  while (b >= a.blkStart[pi + 1]) ++pi;
  const int rel = b - a.blkStart[pi];
  const int nbx = a.nbx[pi];
  const int q0 = (rel % nbx) * 32;       // src-row block
  const int p0 = (rel / nbx) * 32;       // src-col block
  const int R = a.R[pi], C = a.C[pi], Q = a.Q[pi];
  const bool isb = a.isb[pi] != 0;
  const void* src = a.src[pi];
  const int tx = threadIdx.x & 31, ty = threadIdx.x >> 5;
#pragma unroll
  for (int y = ty; y < 32; y += 8) {
    int r = q0 + y, c = p0 + tx;
    float v = 0.f;
    if (r < R && c < C)
      v = isb ? (float)((const bf16*)src)[(long)r * C + c]
              : ((const float*)src)[(long)r * C + c];
    tile[y][tx] = v;
  }
  __syncthreads();
  bf16* dst = a.dst[pi];
#pragma unroll
  for (int y = ty; y < 32; y += 8)
    dst[(long)(p0 + y) * Q + (q0 + tx)] = (bf16)tile[tx][y];
}

// fp32 -> bf16, 4 buffers per launch (blockIdx.z), n % 4 == 0
struct CvtB { const float* s[4]; bf16* d[4]; long n[4]; };
__global__ void cvt_batch(CvtB cb)
{
  const float* s = cb.s[blockIdx.z];
  bf16* d = cb.d[blockIdx.z];
  long i = ((long)blockIdx.x * blockDim.x + threadIdx.x) * 4;
  if (i >= cb.n[blockIdx.z]) return;
  float4 v = *(const float4*)(s + i);
  bf16x4 o = {(bf16)v.x, (bf16)v.y, (bf16)v.z, (bf16)v.w};
  *(bf16x4*)(d + i) = o;
}

// Student-t q per row (one wave per row). NO atomics — colsum done separately.
__global__ void qkern(const float* __restrict__ z, const float* __restrict__ cl,
                      float* __restrict__ qout)
{
  const int n = blockIdx.x;
  const int lane = threadIdx.x;
  float d0 = 0, d1 = 0, d2 = 0, d3 = 0, d4 = 0;
  for (int s = lane; s < 819; s += 64) {
    float zv = z[(long)n * 819 + s];
    float t0 = zv - cl[0 * 819 + s]; d0 += t0 * t0;
    float t1 = zv - cl[1 * 819 + s]; d1 += t1 * t1;
    float t2 = zv - cl[2 * 819 + s]; d2 += t2 * t2;
    float t3 = zv - cl[3 * 819 + s]; d3 += t3 * t3;
    float t4 = zv - cl[4 * 819 + s]; d4 += t4 * t4;
  }
#pragma unroll
  for (int off = 32; off > 0; off >>= 1) {
    d0 += __shfl_xor(d0, off);
    d1 += __shfl_xor(d1, off);
    d2 += __shfl_xor(d2, off);
    d3 += __shfl_xor(d3, off);
    d4 += __shfl_xor(d4, off);
  }
  if (lane == 0) {
    float q0 = 1.f / (1.f + d0), q1 = 1.f / (1.f + d1), q2 = 1.f / (1.f + d2);
    float q3 = 1.f / (1.f + d3), q4 = 1.f / (1.f + d4);
    float inv = 1.f / (q0 + q1 + q2 + q3 + q4);
    float* qr = qout + (long)n * 5;
    qr[0] = q0 * inv; qr[1] = q1 * inv; qr[2] = q2 * inv;
    qr[3] = q3 * inv; qr[4] = q4 * inv;
  }
}

__global__ void colsum_kern(const float* __restrict__ q, float* __restrict__ colsum)
{
  __shared__ float red[256];
  const int k = blockIdx.x;
  float s = 0.f;
  for (int n = threadIdx.x; n < 4096; n += 256) s += q[(long)n * 5 + k];
  red[threadIdx.x] = s;
  __syncthreads();
  for (int w = 128; w > 0; w >>= 1) {
    if (threadIdx.x < w) red[threadIdx.x] += red[threadIdx.x + w];
    __syncthreads();
  }
  if (threadIdx.x == 0) colsum[k] = red[0];
}

__global__ void pkern(const float* __restrict__ q, const float* __restrict__ colsum,
                      float* __restrict__ p)
{
  int n = blockIdx.x * blockDim.x + threadIdx.x;
  if (n >= 4096) return;
  float w[5], s = 0.f;
#pragma unroll
  for (int k = 0; k < 5; ++k) {
    float qv = q[(long)n * 5 + k];
    w[k] = qv * qv / colsum[k];
    s += w[k];
  }
  float inv = 1.f / s;
#pragma unroll
  for (int k = 0; k < 5; ++k) p[(long)n * 5 + k] = w[k] * inv;
}

struct BiasArgs {
  const float* src[8];
  float* dst[8];
  int n[8];
  int np[8];
};

__global__ void biaspad(BiasArgs a)
{
  int b = blockIdx.x;
  for (int i = threadIdx.x; i < a.np[b]; i += blockDim.x)
    a.dst[b][i] = (i < a.n[b]) ? a.src[b][i] : 0.f;
}

// ---------------------------------------------------------------------------
extern "C" void kernel_launch(void* const* d_in, const int* in_sizes, int n_in,
                              void* d_out, int out_size, void* d_ws, size_t ws_size,
                              hipStream_t stream)
{
  (void)in_sizes; (void)n_in; (void)out_size; (void)ws_size;
  const float* x0    = (const float*)d_in[0];
  const float* x1    = (const float*)d_in[1];
  const float* we    = (const float*)d_in[2];
  const float* g0    = (const float*)d_in[3];
  const float* g1    = (const float*)d_in[4];
  const float* We1_0 = (const float*)d_in[5];
  const float* be1_0 = (const float*)d_in[6];
  const float* We2_0 = (const float*)d_in[7];
  const float* be2_0 = (const float*)d_in[8];
  const float* We1_1 = (const float*)d_in[9];
  const float* be1_1 = (const float*)d_in[10];
  const float* We2_1 = (const float*)d_in[11];
  const float* be2_1 = (const float*)d_in[12];
  const float* Wd1_0 = (const float*)d_in[13];
  const float* bd1_0 = (const float*)d_in[14];
  const float* Wd2_0 = (const float*)d_in[15];
  const float* bd2_0 = (const float*)d_in[16];
  const float* Wd1_1 = (const float*)d_in[17];
  const float* bd1_1 = (const float*)d_in[18];
  const float* Wd2_1 = (const float*)d_in[19];
  const float* bd2_1 = (const float*)d_in[20];
  const float* Ww0   = (const float*)d_in[21];
  const float* Ww1   = (const float*)d_in[22];
  const float* Wf0   = (const float*)d_in[23];
  const float* Wf1   = (const float*)d_in[24];
  const float* clus  = (const float*)d_in[25];
  float* out = (float*)d_out;

  const size_t OFF_REC0 = 0;
  const size_t OFF_REC1 = 4194304;
  const size_t OFF_ADJ0 = 9437184;
  const size_t OFF_ADJ1 = 26214400;
  const size_t OFF_Z    = 42991616;
  const size_t OFF_P    = 46346240;
  const size_t OFF_Q    = 46366720;
  const size_t OFF_CL   = 46387200;

  char* ws = (char*)d_ws;
  size_t off = 0;
  auto alloc = [&](size_t bytes) -> void* {
    off = (off + 255) & ~(size_t)255;
    void* p = ws + off;
    off += bytes;
    return p;
  };
  const long N = 4096;
  bf16* g0b   = (bf16*)alloc((size_t)N * 4096 * 2);
  bf16* g1b   = (bf16*)alloc((size_t)N * 4096 * 2);
  bf16* x0b   = (bf16*)alloc((size_t)N * 1024 * 2);
  bf16* x1b   = (bf16*)alloc((size_t)N * 1280 * 2);
  bf16* BTe10 = (bf16*)alloc((size_t)896 * 1024 * 2);
  bf16* BTe20 = (bf16*)alloc((size_t)896 * 896 * 2);
  bf16* BTe11 = (bf16*)alloc((size_t)1024 * 1280 * 2);
  bf16* BTe21 = (bf16*)alloc((size_t)896 * 1024 * 2);
  bf16* BTd10 = (bf16*)alloc((size_t)896 * 896 * 2);
  bf16* BTd20 = (bf16*)alloc((size_t)1024 * 896 * 2);
  bf16* BTd11 = (bf16*)alloc((size_t)1024 * 896 * 2);
  bf16* BTd21 = (bf16*)alloc((size_t)1280 * 1024 * 2);
  bf16* BTw0  = (bf16*)alloc((size_t)896 * 896 * 2);
  bf16* BTw1  = (bf16*)alloc((size_t)896 * 896 * 2);
  bf16* BTf0  = (bf16*)alloc((size_t)896 * 896 * 2);
  bf16* BTf1  = (bf16*)alloc((size_t)896 * 896 * 2);
  float* pbe10 = (float*)alloc(896 * 4);
  float* pbe20 = (float*)alloc(896 * 4);
  float* pbe11 = (float*)alloc(1024 * 4);
  float* pbe21 = (float*)alloc(896 * 4);
  float* pbd10 = (float*)alloc(896 * 4);
  float* pbd20 = (float*)alloc(1024 * 4);
  float* pbd11 = (float*)alloc(1024 * 4);
  float* pbd21 = (float*)alloc(1280 * 4);
  bf16* zb     = (bf16*)alloc((size_t)N * 896 * 2);
  float* colsum = (float*)alloc(64);
  bf16* xT0 = (bf16*)alloc((size_t)1024 * 4096 * 2);  // transposed operands, ch 0
  bf16* xT1 = (bf16*)alloc((size_t)1280 * 4096 * 2);  // transposed operands, ch 1
  bf16* u0  = (bf16*)alloc((size_t)N * 1024 * 2);
  bf16* u1  = (bf16*)alloc((size_t)N * 1280 * 2);
  bf16* h0  = (bf16*)alloc((size_t)N * 896 * 2);
  bf16* h1b = (bf16*)alloc((size_t)N * 1024 * 2);
  bf16* y0  = (bf16*)alloc((size_t)N * 896 * 2);
  bf16* y1  = (bf16*)alloc((size_t)N * 896 * 2);
  bf16* t0b = (bf16*)alloc((size_t)N * 896 * 2);
  bf16* t1b = (bf16*)alloc((size_t)N * 896 * 2);
  float* partA = (float*)alloc((size_t)2 * N * 1024 * 4);  // split-K partials
  float* partB = (float*)alloc((size_t)2 * N * 1024 * 4);

  // ---- input conversions (one launch: g0,g1,x0,x1) ------------------------
  {
    CvtB cb;
    cb.s[0] = g0; cb.d[0] = g0b; cb.n[0] = N * 4096;
    cb.s[1] = g1; cb.d[1] = g1b; cb.n[1] = N * 4096;
    cb.s[2] = x0; cb.d[2] = x0b; cb.n[2] = N * 1024;
    cb.s[3] = x1; cb.d[3] = x1b; cb.n[3] = N * 1280;
    cvt_batch<<<dim3(16384, 1, 4), 256, 0, stream>>>(cb);
  }

  // ---- 12 weight transposes in one launch ---------------------------------
  {
    TrBatch tb{};
    tb.nprob = 0; tb.blkStart[0] = 0;
    auto addTr = [&](const void* s, bf16* d, int R, int C, int P, int Q, int isb) {
      int i = tb.nprob++;
      tb.src[i] = s; tb.dst[i] = d;
      tb.R[i] = R; tb.C[i] = C; tb.Q[i] = Q; tb.isb[i] = isb;
      tb.nbx[i] = Q / 32;
      tb.blkStart[i + 1] = tb.blkStart[i] + (Q / 32) * (P / 32);
    };
    addTr(We1_0, BTe10, 1024, 819, 896, 1024, 0);
    addTr(We2_0, BTe20, 819, 819, 896, 896, 0);
    addTr(We1_1, BTe11, 1280, 1024, 1024, 1280, 0);
    addTr(We2_1, BTe21, 1024, 819, 896, 1024, 0);
    addTr(Wd1_0, BTd10, 819, 819, 896, 896, 0);
    addTr(Wd2_0, BTd20, 819, 1024, 1024, 896, 0);
    addTr(Wd1_1, BTd11, 819, 1024, 1024, 896, 0);
    addTr(Wd2_1, BTd21, 1024, 1280, 1280, 1024, 0);
    addTr(Ww0, BTw0, 819, 819, 896, 896, 0);
    addTr(Ww1, BTw1, 819, 819, 896, 896, 0);
    addTr(Wf0, BTf0, 819, 819, 896, 896, 0);
    addTr(Wf1, BTf1, 819, 819, 896, 896, 0);
    tr_batch<<<tb.blkStart[tb.nprob], 256, 0, stream>>>(tb);
  }

  BiasArgs ba;
  {
    const float* bsrc[8] = {be1_0, be2_0, be1_1, be2_1, bd1_0, bd2_0, bd1_1, bd2_1};
    float* bdst[8] = {pbe10, pbe20, pbe11, pbe21, pbd10, pbd20, pbd11, pbd21};
    int bn_[8] = {819, 819, 1024, 819, 819, 1024, 1024, 1280};
    int bnp[8] = {896, 896, 1024, 896, 896, 1024, 1024, 1280};
    for (int i = 0; i < 8; ++i) { ba.src[i] = bsrc[i]; ba.dst[i] = bdst[i]; ba.n[i] = bn_[i]; ba.np[i] = bnp[i]; }
  }
  biaspad<<<8, 256, 0, stream>>>(ba);

  // ---- batched GEMM helpers ----------------------------------------------
  GBatch gb{};
  int np = 0, maxN = 0;
  auto beg = [&]() { np = 0; maxN = 0; gb = GBatch{}; };
  auto add = [&](const bf16* A, const bf16* Bt, const float* bias,
                 float* Cf, int ldcf, bf16* Cb, int ldcb,
                 int K, int Npad, int Ntrue, int act) {
    gb.p[np].A = A; gb.p[np].Bt = Bt; gb.p[np].bias = bias;
    gb.p[np].Cf = Cf; gb.p[np].Cb = Cb; gb.p[np].Cp = nullptr;
    gb.p[np].K = K; gb.p[np].Npad = Npad;
    gb.p[np].ldcf = ldcf; gb.p[np].ldcb = ldcb;
    gb.p[np].Ntrue = Ntrue; gb.p[np].act = act;
    ++np;
    if (Npad > maxN) maxN = Npad;
  };
  auto addS = [&](const bf16* A, const bf16* Bt, float* Cp, int K, int Npad) {
    gb.p[np].A = A; gb.p[np].Bt = Bt; gb.p[np].bias = nullptr;
    gb.p[np].Cf = nullptr; gb.p[np].Cb = nullptr; gb.p[np].Cp = Cp;
    gb.p[np].K = K; gb.p[np].Npad = Npad;
    gb.p[np].ldcf = 0; gb.p[np].ldcb = 0; gb.p[np].Ntrue = 0; gb.p[np].act = 0;
    ++np;
    if (Npad > maxN) maxN = Npad;
  };
  auto goN = [&]() { gemm_nt_batch<1><<<dim3(maxN / 128, 32, np), 256, 0, stream>>>(gb); };
  auto goS = [&]() { gemm_nt_batch<2><<<dim3(maxN / 128, 32, np * 2), 256, 0, stream>>>(gb); };
  auto comb = [&](const float* bias0, float* Cf0, int ldf0, int Nt0, bf16* Cb0, int ldb0, int Np0, int act0,
                  const float* bias1, float* Cf1, int ldf1, int Nt1, bf16* Cb1, int ldb1, int Np1, int act1) {
    CBatch cb;
    cb.p[0] = {partA, bias0, Cf0, Cb0, Np0, ldf0, ldb0, Nt0, act0};
    cb.p[1] = {partB, bias1, Cf1, Cb1, Np1, ldf1, ldb1, Nt1, act1};
    combine_batch<<<dim3(4096, 1, 2), 256, 0, stream>>>(cb);
  };
  auto trb2 = [&](const bf16* s0, int C0, const bf16* s1, int C1) {
    TrBatch tb{};
    tb.nprob = 2; tb.blkStart[0] = 0;
    tb.src[0] = s0; tb.dst[0] = xT0; tb.R[0] = 4096; tb.C[0] = C0; tb.Q[0] = 4096;
    tb.isb[0] = 1; tb.nbx[0] = 128; tb.blkStart[1] = 128 * (C0 / 32);
    tb.src[1] = s1; tb.dst[1] = xT1; tb.R[1] = 4096; tb.C[1] = C1; tb.Q[1] = 4096;
    tb.isb[1] = 1; tb.nbx[1] = 128; tb.blkStart[2] = tb.blkStart[1] + 128 * (C1 / 32);
    tr_batch<<<tb.blkStart[2], 256, 0, stream>>>(tb);
  };

  // ---- encoders, reassociated: h1 = tanh(g@(x@We1)+b); h2 = tanh(g@(h1@We2)+b)
  beg();  // S1: w = x @ We1 (small K, no act)
  add(x0b, BTe10, nullptr, nullptr, 0, u0, 896, 1024, 896, 896, 0);
  add(x1b, BTe11, nullptr, nullptr, 0, u1, 1024, 1280, 1024, 1024, 0);
  goN();
  trb2(u0, 896, u1, 1024);                                   // w^T
  beg();  // S2: h1 = tanh(g @ w + be1)  [split-K, K=4096]
  addS(g0b, xT0, partA, 4096, 896);
  addS(g1b, xT1, partB, 4096, 1024);
  goS();
  comb(pbe10, nullptr, 0, 0, h0, 896, 896, 1,
       pbe11, nullptr, 0, 0, h1b, 1024, 1024, 1);
  beg();  // S3: s = h1 @ We2 (small K, no act)
  add(h0, BTe20, nullptr, nullptr, 0, u0, 896, 896, 896, 896, 0);
  add(h1b, BTe21, nullptr, nullptr, 0, u1, 896, 1024, 896, 896, 0);
  goN();
  trb2(u0, 896, u1, 896);                                    // s^T
  beg();  // S4: h2 = tanh(g @ s + be2)  [split-K] -> fused combine + z
  addS(g0b, xT0, partA, 4096, 896);
  addS(g1b, xT1, partB, 4096, 896);
  goS();
  combz<<<4096, 224, 0, stream>>>(partA, partB, pbe20, pbe21, we, out + OFF_Z, zb);

  // ---- four z-projections in one launch ----------------------------------
  beg();  // E: y0, y1 (act0), t0, t1 (act1)
  add(zb, BTw0, nullptr, nullptr, 0, y0, 896, 896, 896, 896, 0);
  add(zb, BTw1, nullptr, nullptr, 0, y1, 896, 896, 896, 896, 0);
  add(zb, BTf0, nullptr, nullptr, 0, t0b, 896, 896, 896, 896, 1);
  add(zb, BTf1, nullptr, nullptr, 0, t1b, 896, 896, 896, 896, 1);
  goN();
  beg();  // F: adj = sigmoid(y @ z^T)
  add(y0, zb, nullptr, out + OFF_ADJ0, 4096, nullptr, 0, 896, 4096, 4096, 2);
  add(y1, zb, nullptr, out + OFF_ADJ1, 4096, nullptr, 0, 896, 4096, 4096, 2);
  goN();

  // ---- feature decoders (0 || 1) -----------------------------------------
  trb2(t0b, 896, t1b, 896);                                  // t^T
  beg();  // G: r = g @ t  [split-K]
  addS(g0b, xT0, partA, 4096, 896);
  addS(g1b, xT1, partB, 4096, 896);
  goS();
  comb(nullptr, nullptr, 0, 0, u0, 896, 896, 0,
       nullptr, nullptr, 0, 0, u1, 896, 896, 0);
  beg();  // H: hr = tanh(r @ Wd1 + b)
  add(u0, BTd10, pbd10, nullptr, 0, h0, 896, 896, 896, 896, 1);
  add(u1, BTd11, pbd11, nullptr, 0, h1b, 1024, 896, 1024, 1024, 1);
  goN();
  trb2(h0, 896, h1b, 1024);                                  // hr^T
  beg();  // I: rin = g @ hr  [split-K]
  addS(g0b, xT0, partA, 4096, 896);
  addS(g1b, xT1, partB, 4096, 1024);
  goS();
  comb(nullptr, nullptr, 0, 0, u0, 896, 896, 0,
       nullptr, nullptr, 0, 0, u1, 1024, 1024, 0);
  beg();  // J: rec = tanh(rin @ Wd2 + b)  (fp32 out)
  add(u0, BTd20, pbd20, out + OFF_REC0, 1024, nullptr, 0, 896, 1024, 1024, 1);
  add(u1, BTd21, pbd21, out + OFF_REC1, 1280, nullptr, 0, 1024, 1280, 1280, 1);
  goN();

  // ---- q / p / cluster ---------------------------------------------------
  qkern<<<4096, 64, 0, stream>>>(out + OFF_Z, clus, out + OFF_Q);
  colsum_kern<<<5, 256, 0, stream>>>(out + OFF_Q, colsum);
  pkern<<<16, 256, 0, stream>>>(out + OFF_Q, colsum, out + OFF_P);
  hipMemcpyAsync(out + OFF_CL, (const void*)clus, 4095 * sizeof(float),
                 hipMemcpyDeviceToDevice, stream);
}

// Round 7
// 1056.925 us; speedup vs baseline: 1.2457x; 1.0144x over previous
//
#include <hip/hip_runtime.h>
#include <hip/hip_bf16.h>
#include <cstdint>
#include <cstddef>

typedef __bf16 bf16;
typedef __attribute__((ext_vector_type(8))) __bf16 bf16x8;
typedef __attribute__((ext_vector_type(4))) __bf16 bf16x4;
typedef __attribute__((ext_vector_type(4))) float f32x4;

// ---------------------------------------------------------------------------
// async global->LDS, 16B per lane (wave-uniform LDS base + lane*16)
__device__ __forceinline__ void gload_lds16(const void* g, void* l) {
  __builtin_amdgcn_global_load_lds(
      (const __attribute__((address_space(1))) uint32_t*)(uintptr_t)g,
      (__attribute__((address_space(3))) uint32_t*)(uintptr_t)l, 16, 0, 0);
}

__device__ __forceinline__ float actf(float v, int act) {
  if (act == 1) return tanhf(v);
  if (act == 2) return 1.f / (1.f + __expf(-v));
  return v;
}

// ---------------------------------------------------------------------------
// Batched NT GEMM, flat 1D grid with per-problem {start, nbx} decode (the
// tr_batch pattern) so problems with different M and N batch with ZERO idle
// blocks. T1 XCD bijection (m204) applied to the flat id: each XCD owns a
// contiguous x-inner chunk -> A-row-tile fetched once per XCD (verified r5:
// split-K FETCH 395->65 MB). BK=64 (r6): 32 MFMA/wave per barrier-pair.
// XOR swizzle over 8 chunks: gc = cs ^ (row&7), involution on both sides.
// Split-K expressed per-entry: {kbeg, kcnt, Cp} (partials fp32, combine
// kernel finishes). biasRow: bias indexed by output ROW (for GEMMs that
// compute W^T @ X^T directly, i.e. transposed-orientation outputs —
// (X@W)^T = W^T X^T with A=W^T (the BT* buffers), Bt=X (row-major input);
// this replaced all four mid-graph transpose passes in r7).
struct GProb {
  const bf16* A; const bf16* Bt; const float* bias;
  float* Cf; bf16* Cb; float* Cp;
  int lda, kbeg, kcnt, nbx, ldcf, ldcb, Ntrue, act, biasRow;
};
struct GBatch { GProb p[4]; int start[5]; };

__global__ __launch_bounds__(256, 2)
void gemm_nt_batch(GBatch b)
{
  // ---- T1: bijective XCD remap over the flat block space ----
  const int T = (int)gridDim.x;
  const int fid = (int)blockIdx.x;
  const int q = T >> 3, r = T & 7;
  const int xcd = fid & 7, idx = fid >> 3;
  const int wid = (xcd < r ? xcd * (q + 1) : r * (q + 1) + (xcd - r) * q) + idx;

  int pi = 0;
  while (wid >= b.start[pi + 1]) ++pi;
  const GProb P = b.p[pi];
  const int rel = wid - b.start[pi];
  const long bn = (long)(rel % P.nbx) * 128;
  const long bm = (long)(rel / P.nbx) * 128;

  __shared__ __align__(16) bf16 As[128 * 64];
  __shared__ __align__(16) bf16 Bs[128 * 64];

  const int lda  = P.lda;
  const int tid  = threadIdx.x;
  const int lane = tid & 63, wave = tid >> 6;
  const int wr = wave >> 1, wc = wave & 1;
  const int l15 = lane & 15, quad = lane >> 4;

  // staging: slot = s*256 + tid; row = slot/8, chunk-slot = slot%8,
  // global chunk = cslot ^ (row&7)  (involution; LDS slot order == lane
  // order as required by global_load_lds: dest = wave-uniform base + lane*16)
  long aoff[4], boff[4];
  int ldsoff[4];
#pragma unroll
  for (int s = 0; s < 4; ++s) {
    int slot = s * 256 + tid;
    int row = slot >> 3, cs = slot & 7;
    int gc = cs ^ (row & 7);
    aoff[s] = (bm + row) * (long)lda + gc * 8;
    boff[s] = (bn + row) * (long)lda + gc * 8;
    ldsoff[s] = (s * 256 + wave * 64) * 8;   // wave-uniform base (elements)
  }

  // fragment reads: MFMA k-slice ks (k = ks*32 + quad*8) wants global chunk
  // ks*4+quad of row r at slot (ks*4+quad)^(r&7); r&7 == l15&7 here.
  const int cfr0 = ((0 * 4 + quad) ^ (l15 & 7)) * 8;
  const int cfr1 = ((1 * 4 + quad) ^ (l15 & 7)) * 8;
  int afr[2][4], bfr[2][4];
#pragma unroll
  for (int i = 0; i < 4; ++i) {
    afr[0][i] = (wr * 64 + i * 16 + l15) * 64 + cfr0;
    afr[1][i] = (wr * 64 + i * 16 + l15) * 64 + cfr1;
    bfr[0][i] = (wc * 64 + i * 16 + l15) * 64 + cfr0;
    bfr[1][i] = (wc * 64 + i * 16 + l15) * 64 + cfr1;
  }

  f32x4 acc[4][4];
#pragma unroll
  for (int i = 0; i < 4; ++i)
#pragma unroll
    for (int j = 0; j < 4; ++j) acc[i][j] = {0.f, 0.f, 0.f, 0.f};

  for (int k0 = P.kbeg; k0 < P.kbeg + P.kcnt; k0 += 64) {
    __syncthreads();                       // protect LDS from previous readers
#pragma unroll
    for (int s = 0; s < 4; ++s) {
      gload_lds16(P.A + aoff[s] + k0, As + ldsoff[s]);
      gload_lds16(P.Bt + boff[s] + k0, Bs + ldsoff[s]);
    }
    __syncthreads();                       // compiler drains vmcnt before barrier

    // two sequential k-slice groups: only 8 fragments live at a time
#pragma unroll
    for (int ks = 0; ks < 2; ++ks) {
      bf16x8 av[4], bv[4];
#pragma unroll
      for (int i = 0; i < 4; ++i) av[i] = *(const bf16x8*)(As + afr[ks][i]);
#pragma unroll
      for (int j = 0; j < 4; ++j) bv[j] = *(const bf16x8*)(Bs + bfr[ks][j]);
#pragma unroll
      for (int i = 0; i < 4; ++i)
#pragma unroll
        for (int j = 0; j < 4; ++j)
          acc[i][j] = __builtin_amdgcn_mfma_f32_16x16x32_bf16(av[i], bv[j], acc[i][j], 0, 0, 0);
    }
  }

  // epilogue: C/D layout col=lane&15, row=quad*4+reg
  const long row0 = bm + wr * 64 + quad * 4;
  const long col0 = bn + wc * 64 + l15;
  if (P.Cp) {
    const int ldp = P.nbx * 128;
#pragma unroll
    for (int i = 0; i < 4; ++i)
#pragma unroll
      for (int j = 0; j < 4; ++j)
#pragma unroll
        for (int t = 0; t < 4; ++t)
          P.Cp[(row0 + i * 16 + t) * (long)ldp + col0 + j * 16] = acc[i][j][t];
  } else {
    const int act = P.act;
#pragma unroll
    for (int i = 0; i < 4; ++i) {
#pragma unroll
      for (int j = 0; j < 4; ++j) {
        long c = col0 + j * 16;
        float bbc = (P.bias && !P.biasRow) ? P.bias[c] : 0.f;
#pragma unroll
        for (int t = 0; t < 4; ++t) {
          long r = row0 + i * 16 + t;
          float bb = P.biasRow ? (P.bias ? P.bias[r] : 0.f) : bbc;
          float v = actf(acc[i][j][t] + bb, act);
          if (P.Cf && c < P.Ntrue) P.Cf[r * P.ldcf + c] = v;
          if (P.Cb) P.Cb[r * P.ldcb + c] = (bf16)v;
        }
      }
    }
  }
}

// ---------------------------------------------------------------------------
// combine: out = act(part[0] + part[1] + bias); fp32 and/or bf16 stores.
struct CProb {
  const float* part; const float* bias;
  float* Cf; bf16* Cb;
  int Npad, ldcf, ldcb, Ntrue, act;
};
struct CBatch { CProb p[2]; };

__global__ void combine_batch(CBatch cb)
{
  const CProb P = cb.p[blockIdx.z];
  const int row = blockIdx.x;
  const int c4 = threadIdx.x * 4;
  if (c4 >= P.Npad) return;
  const long base = (long)row * P.Npad + c4;
  float4 a = *(const float4*)(P.part + base);
  float4 b = *(const float4*)(P.part + (long)4096 * P.Npad + base);
  float v[4] = {a.x + b.x, a.y + b.y, a.z + b.z, a.w + b.w};
  if (P.bias) {
    float4 bi = *(const float4*)(P.bias + c4);
    v[0] += bi.x; v[1] += bi.y; v[2] += bi.z; v[3] += bi.w;
  }
#pragma unroll
  for (int t = 0; t < 4; ++t) v[t] = actf(v[t], P.act);
  if (P.Cf && c4 < P.Ntrue) {
    float* o = P.Cf + (long)row * P.ldcf + c4;
    o[0] = v[0]; o[1] = v[1]; o[2] = v[2]; o[3] = v[3];
  }
  if (P.Cb) {
    bf16x4 o = {(bf16)v[0], (bf16)v[1], (bf16)v[2], (bf16)v[3]};
    *(bf16x4*)(P.Cb + (long)row * P.ldcb + c4) = o;
  }
}

// ---------------------------------------------------------------------------
// fused S4-combine + z: h2_i = tanh(partX0+partX1+be2_i); z = weighted merge.
// 224 threads x 4 cols = 896. Writes z fp32 [4096,819] + zb bf16 [4096,896].
__global__ void combz(const float* __restrict__ pA, const float* __restrict__ pB,
                      const float* __restrict__ bA, const float* __restrict__ bB,
                      const float* __restrict__ we, float* __restrict__ zout,
                      bf16* __restrict__ zb)
{
  const int n = blockIdx.x;
  const int c = threadIdx.x * 4;
  const long base = (long)n * 896 + c;
  const long half = (long)4096 * 896;
  float4 a0 = *(const float4*)(pA + base);
  float4 a1 = *(const float4*)(pA + half + base);
  float4 b0 = *(const float4*)(pB + base);
  float4 b1 = *(const float4*)(pB + half + base);
  float4 ba = *(const float4*)(bA + c);
  float4 bb = *(const float4*)(bB + c);
  const float w0 = we[n * 2], w1 = we[n * 2 + 1];
  const float inv = 1.f / (w0 + w1);
  float h0[4] = {a0.x + a1.x + ba.x, a0.y + a1.y + ba.y, a0.z + a1.z + ba.z, a0.w + a1.w + ba.w};
  float h1[4] = {b0.x + b1.x + bb.x, b0.y + b1.y + bb.y, b0.z + b1.z + bb.z, b0.w + b1.w + bb.w};
  bf16x4 o;
#pragma unroll
  for (int t = 0; t < 4; ++t) {
    float v = (w0 * tanhf(h0[t]) + w1 * tanhf(h1[t])) * inv;
    o[t] = (bf16)v;
    if (c + t < 819) zout[(long)n * 819 + c + t] = v;
  }
  *(bf16x4*)(zb + base) = o;
}

// ---------------------------------------------------------------------------
// Batched padded transpose: dst[P x Q] = src^T zero-padded (weight setup only).
struct TrBatch {
  const void* src[14]; bf16* dst[14];
  int R[14], C[14], Q[14], nbx[14], isb[14];
  int blkStart[15];
  int nprob;
};

__global__ void tr_batch(TrBatch a)
{
  __shared__ float tile[32][33];
  int pi = 0, b = blockIdx.x;
  while (b >= a.blkStart[pi + 1]) ++pi;
  const int rel = b - a.blkStart[pi];
  const int nbx = a.nbx[pi];
  const int q0 = (rel % nbx) * 32;       // src-row block
  const int p0 = (rel / nbx) * 32;       // src-col block
  const int R = a.R[pi], C = a.C[pi], Q = a.Q[pi];
  const bool isb = a.isb[pi] != 0;
  const void* src = a.src[pi];
  const int tx = threadIdx.x & 31, ty = threadIdx.x >> 5;
#pragma unroll
  for (int y = ty; y < 32; y += 8) {
    int r = q0 + y, c = p0 + tx;
    float v = 0.f;
    if (r < R && c < C)
      v = isb ? (float)((const bf16*)src)[(long)r * C + c]
              : ((const float*)src)[(long)r * C + c];
    tile[y][tx] = v;
  }
  __syncthreads();
  bf16* dst = a.dst[pi];
#pragma unroll
  for (int y = ty; y < 32; y += 8)
    dst[(long)(p0 + y) * Q + (q0 + tx)] = (bf16)tile[tx][y];
}

// fp32 -> bf16, 4 buffers per launch (blockIdx.z), n % 4 == 0
struct CvtB { const float* s[4]; bf16* d[4]; long n[4]; };
__global__ void cvt_batch(CvtB cb)
{
  const float* s = cb.s[blockIdx.z];
  bf16* d = cb.d[blockIdx.z];
  long i = ((long)blockIdx.x * blockDim.x + threadIdx.x) * 4;
  if (i >= cb.n[blockIdx.z]) return;
  float4 v = *(const float4*)(s + i);
  bf16x4 o = {(bf16)v.x, (bf16)v.y, (bf16)v.z, (bf16)v.w};
  *(bf16x4*)(d + i) = o;
}

// Student-t q per row (one wave per row). NO atomics — colsum done separately.
__global__ void qkern(const float* __restrict__ z, const float* __restrict__ cl,
                      float* __restrict__ qout)
{
  const int n = blockIdx.x;
  const int lane = threadIdx.x;
  float d0 = 0, d1 = 0, d2 = 0, d3 = 0, d4 = 0;
  for (int s = lane; s < 819; s += 64) {
    float zv = z[(long)n * 819 + s];
    float t0 = zv - cl[0 * 819 + s]; d0 += t0 * t0;
    float t1 = zv - cl[1 * 819 + s]; d1 += t1 * t1;
    float t2 = zv - cl[2 * 819 + s]; d2 += t2 * t2;
    float t3 = zv - cl[3 * 819 + s]; d3 += t3 * t3;
    float t4 = zv - cl[4 * 819 + s]; d4 += t4 * t4;
  }
#pragma unroll
  for (int off = 32; off > 0; off >>= 1) {
    d0 += __shfl_xor(d0, off);
    d1 += __shfl_xor(d1, off);
    d2 += __shfl_xor(d2, off);
    d3 += __shfl_xor(d3, off);
    d4 += __shfl_xor(d4, off);
  }
  if (lane == 0) {
    float q0 = 1.f / (1.f + d0), q1 = 1.f / (1.f + d1), q2 = 1.f / (1.f + d2);
    float q3 = 1.f / (1.f + d3), q4 = 1.f / (1.f + d4);
    float inv = 1.f / (q0 + q1 + q2 + q3 + q4);
    float* qr = qout + (long)n * 5;
    qr[0] = q0 * inv; qr[1] = q1 * inv; qr[2] = q2 * inv;
    qr[3] = q3 * inv; qr[4] = q4 * inv;
  }
}

__global__ void colsum_kern(const float* __restrict__ q, float* __restrict__ colsum)
{
  __shared__ float red[256];
  const int k = blockIdx.x;
  float s = 0.f;
  for (int n = threadIdx.x; n < 4096; n += 256) s += q[(long)n * 5 + k];
  red[threadIdx.x] = s;
  __syncthreads();
  for (int w = 128; w > 0; w >>= 1) {
    if (threadIdx.x < w) red[threadIdx.x] += red[threadIdx.x + w];
    __syncthreads();
  }
  if (threadIdx.x == 0) colsum[k] = red[0];
}

__global__ void pkern(const float* __restrict__ q, const float* __restrict__ colsum,
                      float* __restrict__ p)
{
  int n = blockIdx.x * blockDim.x + threadIdx.x;
  if (n >= 4096) return;
  float w[5], s = 0.f;
#pragma unroll
  for (int k = 0; k < 5; ++k) {
    float qv = q[(long)n * 5 + k];
    w[k] = qv * qv / colsum[k];
    s += w[k];
  }
  float inv = 1.f / s;
#pragma unroll
  for (int k = 0; k < 5; ++k) p[(long)n * 5 + k] = w[k] * inv;
}

struct BiasArgs {
  const float* src[8];
  float* dst[8];
  int n[8];
  int np[8];
};

__global__ void biaspad(BiasArgs a)
{
  int b = blockIdx.x;
  for (int i = threadIdx.x; i < a.np[b]; i += blockDim.x)
    a.dst[b][i] = (i < a.n[b]) ? a.src[b][i] : 0.f;
}

// ---------------------------------------------------------------------------
extern "C" void kernel_launch(void* const* d_in, const int* in_sizes, int n_in,
                              void* d_out, int out_size, void* d_ws, size_t ws_size,
                              hipStream_t stream)
{
  (void)in_sizes; (void)n_in; (void)out_size; (void)ws_size;
  const float* x0    = (const float*)d_in[0];
  const float* x1    = (const float*)d_in[1];
  const float* we    = (const float*)d_in[2];
  const float* g0    = (const float*)d_in[3];
  const float* g1    = (const float*)d_in[4];
  const float* We1_0 = (const float*)d_in[5];
  const float* be1_0 = (const float*)d_in[6];
  const float* We2_0 = (const float*)d_in[7];
  const float* be2_0 = (const float*)d_in[8];
  const float* We1_1 = (const float*)d_in[9];
  const float* be1_1 = (const float*)d_in[10];
  const float* We2_1 = (const float*)d_in[11];
  const float* be2_1 = (const float*)d_in[12];
  const float* Wd1_0 = (const float*)d_in[13];
  const float* bd1_0 = (const float*)d_in[14];
  const float* Wd2_0 = (const float*)d_in[15];
  const float* bd2_0 = (const float*)d_in[16];
  const float* Wd1_1 = (const float*)d_in[17];
  const float* bd1_1 = (const float*)d_in[18];
  const float* Wd2_1 = (const float*)d_in[19];
  const float* bd2_1 = (const float*)d_in[20];
  const float* Ww0   = (const float*)d_in[21];
  const float* Ww1   = (const float*)d_in[22];
  const float* Wf0   = (const float*)d_in[23];
  const float* Wf1   = (const float*)d_in[24];
  const float* clus  = (const float*)d_in[25];
  float* out = (float*)d_out;

  const size_t OFF_REC0 = 0;
  const size_t OFF_REC1 = 4194304;
  const size_t OFF_ADJ0 = 9437184;
  const size_t OFF_ADJ1 = 26214400;
  const size_t OFF_Z    = 42991616;
  const size_t OFF_P    = 46346240;
  const size_t OFF_Q    = 46366720;
  const size_t OFF_CL   = 46387200;

  char* ws = (char*)d_ws;
  size_t off = 0;
  auto alloc = [&](size_t bytes) -> void* {
    off = (off + 255) & ~(size_t)255;
    void* p = ws + off;
    off += bytes;
    return p;
  };
  const long N = 4096;
  bf16* g0b   = (bf16*)alloc((size_t)N * 4096 * 2);
  bf16* g1b   = (bf16*)alloc((size_t)N * 4096 * 2);
  bf16* x0b   = (bf16*)alloc((size_t)N * 1024 * 2);
  bf16* x1b   = (bf16*)alloc((size_t)N * 1280 * 2);
  bf16* BTe10 = (bf16*)alloc((size_t)896 * 1024 * 2);
  bf16* BTe20 = (bf16*)alloc((size_t)896 * 896 * 2);
  bf16* BTe11 = (bf16*)alloc((size_t)1024 * 1280 * 2);
  bf16* BTe21 = (bf16*)alloc((size_t)896 * 1024 * 2);
  bf16* BTd10 = (bf16*)alloc((size_t)896 * 896 * 2);
  bf16* BTd20 = (bf16*)alloc((size_t)1024 * 896 * 2);
  bf16* BTd11 = (bf16*)alloc((size_t)1024 * 896 * 2);
  bf16* BTd21 = (bf16*)alloc((size_t)1280 * 1024 * 2);
  bf16* BTw0  = (bf16*)alloc((size_t)896 * 896 * 2);
  bf16* BTw1  = (bf16*)alloc((size_t)896 * 896 * 2);
  bf16* BTf0  = (bf16*)alloc((size_t)896 * 896 * 2);
  bf16* BTf1  = (bf16*)alloc((size_t)896 * 896 * 2);
  float* pbe10 = (float*)alloc(896 * 4);
  float* pbe20 = (float*)alloc(896 * 4);
  float* pbe11 = (float*)alloc(1024 * 4);
  float* pbe21 = (float*)alloc(896 * 4);
  float* pbd10 = (float*)alloc(896 * 4);
  float* pbd20 = (float*)alloc(1024 * 4);
  float* pbd11 = (float*)alloc(1024 * 4);
  float* pbd21 = (float*)alloc(1280 * 4);
  bf16* zb     = (bf16*)alloc((size_t)N * 896 * 2);
  float* colsum = (float*)alloc(64);
  bf16* xT0 = (bf16*)alloc((size_t)1024 * 4096 * 2);  // transposed operands, ch 0
  bf16* xT1 = (bf16*)alloc((size_t)1280 * 4096 * 2);  // transposed operands, ch 1
  bf16* u0  = (bf16*)alloc((size_t)N * 1024 * 2);
  bf16* u1  = (bf16*)alloc((size_t)N * 1280 * 2);
  bf16* h0  = (bf16*)alloc((size_t)N * 896 * 2);
  bf16* h1b = (bf16*)alloc((size_t)N * 1024 * 2);
  bf16* y0  = (bf16*)alloc((size_t)N * 896 * 2);
  bf16* y1  = (bf16*)alloc((size_t)N * 896 * 2);
  float* partA = (float*)alloc((size_t)2 * N * 1024 * 4);  // split-K partials
  float* partB = (float*)alloc((size_t)2 * N * 1024 * 4);

  // ---- input conversions (one launch: g0,g1,x0,x1) ------------------------
  {
    CvtB cb;
    cb.s[0] = g0; cb.d[0] = g0b; cb.n[0] = N * 4096;
    cb.s[1] = g1; cb.d[1] = g1b; cb.n[1] = N * 4096;
    cb.s[2] = x0; cb.d[2] = x0b; cb.n[2] = N * 1024;
    cb.s[3] = x1; cb.d[3] = x1b; cb.n[3] = N * 1280;
    cvt_batch<<<dim3(16384, 1, 4), 256, 0, stream>>>(cb);
  }

  // ---- 12 weight transposes in one launch ---------------------------------
  {
    TrBatch tb{};
    tb.nprob = 0; tb.blkStart[0] = 0;
    auto addTr = [&](const void* s, bf16* d, int R, int C, int P, int Q, int isb) {
      int i = tb.nprob++;
      tb.src[i] = s; tb.dst[i] = d;
      tb.R[i] = R; tb.C[i] = C; tb.Q[i] = Q; tb.isb[i] = isb;
      tb.nbx[i] = Q / 32;
      tb.blkStart[i + 1] = tb.blkStart[i] + (Q / 32) * (P / 32);
    };
    addTr(We1_0, BTe10, 1024, 819, 896, 1024, 0);
    addTr(We2_0, BTe20, 819, 819, 896, 896, 0);
    addTr(We1_1, BTe11, 1280, 1024, 1024, 1280, 0);
    addTr(We2_1, BTe21, 1024, 819, 896, 1024, 0);
    addTr(Wd1_0, BTd10, 819, 819, 896, 896, 0);
    addTr(Wd2_0, BTd20, 819, 1024, 1024, 896, 0);
    addTr(Wd1_1, BTd11, 819, 1024, 1024, 896, 0);
    addTr(Wd2_1, BTd21, 1024, 1280, 1280, 1024, 0);
    addTr(Ww0, BTw0, 819, 819, 896, 896, 0);
    addTr(Ww1, BTw1, 819, 819, 896, 896, 0);
    addTr(Wf0, BTf0, 819, 819, 896, 896, 0);
    addTr(Wf1, BTf1, 819, 819, 896, 896, 0);
    tr_batch<<<tb.blkStart[tb.nprob], 256, 0, stream>>>(tb);
  }

  BiasArgs ba;
  {
    const float* bsrc[8] = {be1_0, be2_0, be1_1, be2_1, bd1_0, bd2_0, bd1_1, bd2_1};
    float* bdst[8] = {pbe10, pbe20, pbe11, pbe21, pbd10, pbd20, pbd11, pbd21};
    int bn_[8] = {819, 819, 1024, 819, 819, 1024, 1024, 1280};
    int bnp[8] = {896, 896, 1024, 896, 896, 1024, 1024, 1280};
    for (int i = 0; i < 8; ++i) { ba.src[i] = bsrc[i]; ba.dst[i] = bdst[i]; ba.n[i] = bn_[i]; ba.np[i] = bnp[i]; }
  }
  biaspad<<<8, 256, 0, stream>>>(ba);

  // ---- batched GEMM helpers (flat grid, per-entry geometry) ---------------
  GBatch gb{};
  int np = 0, tot = 0;
  auto beg = [&]() { np = 0; tot = 0; gb = GBatch{}; gb.start[0] = 0; };
  auto addE = [&](const bf16* A, const bf16* Bt, const float* bias, int biasRow,
                  float* Cf, int ldcf, int Ntrue, bf16* Cb, int ldcb,
                  float* Cp, int lda, int kbeg, int kcnt, int M, int Nn, int act) {
    GProb& p = gb.p[np];
    p.A = A; p.Bt = Bt; p.bias = bias; p.Cf = Cf; p.Cb = Cb; p.Cp = Cp;
    p.lda = lda; p.kbeg = kbeg; p.kcnt = kcnt; p.nbx = Nn / 128;
    p.ldcf = ldcf; p.ldcb = ldcb; p.Ntrue = Ntrue; p.act = act; p.biasRow = biasRow;
    tot += (Nn / 128) * (M / 128);
    ++np; gb.start[np] = tot;
  };
  // normal-orientation GEMM (col bias)
  auto add = [&](const bf16* A, const bf16* Bt, const float* bias,
                 float* Cf, int ldcf, int Ntrue, bf16* Cb, int ldcb,
                 int K, int M, int Nn, int act) {
    addE(A, Bt, bias, 0, Cf, ldcf, Ntrue, Cb, ldcb, nullptr, K, 0, K, M, Nn, act);
  };
  // transposed-orientation GEMM (A=W^T, Bt=X row-major; row bias)
  auto addT = [&](const bf16* A, const bf16* Bt, const float* biasR,
                  bf16* Ct, int K, int M, int act) {
    addE(A, Bt, biasR, 1, nullptr, 0, 0, Ct, 4096, nullptr, K, 0, K, M, 4096, act);
  };
  // split-K pair of entries (fp32 partials)
  auto addS = [&](const bf16* A, const bf16* Bt, float* Cp, int K, int Nn) {
    addE(A, Bt, nullptr, 0, nullptr, 0, 0, nullptr, 0, Cp, K, 0, K / 2, 4096, Nn, 0);
    addE(A, Bt, nullptr, 0, nullptr, 0, 0, nullptr, 0,
         Cp + (size_t)4096 * Nn, K, K / 2, K / 2, 4096, Nn, 0);
  };
  auto go = [&]() {
    for (int k = np; k < 4; ++k) gb.start[k + 1] = tot;
    gemm_nt_batch<<<tot, 256, 0, stream>>>(gb);
  };
  auto comb = [&](const float* bias0, float* Cf0, int ldf0, int Nt0, bf16* Cb0, int ldb0, int Np0, int act0,
                  const float* bias1, float* Cf1, int ldf1, int Nt1, bf16* Cb1, int ldb1, int Np1, int act1) {
    CBatch cb;
    cb.p[0] = {partA, bias0, Cf0, Cb0, Np0, ldf0, ldb0, Nt0, act0};
    cb.p[1] = {partB, bias1, Cf1, Cb1, Np1, ldf1, ldb1, Nt1, act1};
    combine_batch<<<dim3(4096, 1, 2), 256, 0, stream>>>(cb);
  };

  // ---- encoders, reassociated: h1 = tanh(g@(x@We1)+b); h2 = tanh(g@(h1@We2)+b)
  beg();  // wT: w^T = We1^T @ x^T  ->  NT(A=BTe1, Bt=x) directly into xT
  addT(BTe10, x0b, nullptr, xT0, 1024, 896, 0);
  addT(BTe11, x1b, nullptr, xT1, 1280, 1024, 0);
  go();
  beg();  // S2: h1 = tanh(g @ w + be1)  [split-K, K=4096]
  addS(g0b, xT0, partA, 4096, 896);
  addS(g1b, xT1, partB, 4096, 1024);
  go();
  comb(pbe10, nullptr, 0, 0, h0, 896, 896, 1,
       pbe11, nullptr, 0, 0, h1b, 1024, 1024, 1);
  beg();  // sT: s^T = We2^T @ h1^T -> NT(A=BTe2, Bt=h1)
  addT(BTe20, h0, nullptr, xT0, 896, 896, 0);
  addT(BTe21, h1b, nullptr, xT1, 1024, 896, 0);
  go();
  beg();  // S4: h2 = tanh(g @ s + be2)  [split-K] -> fused combine + z
  addS(g0b, xT0, partA, 4096, 896);
  addS(g1b, xT1, partB, 4096, 896);
  go();
  combz<<<4096, 224, 0, stream>>>(partA, partB, pbe20, pbe21, we, out + OFF_Z, zb);

  // ---- four z-projections in one launch (t produced pre-transposed) -------
  beg();  // E: y0, y1 normal; t0^T, t1^T = tanh(Wf^T @ z^T) into xT
  add(zb, BTw0, nullptr, nullptr, 0, 0, y0, 896, 896, 4096, 896, 0);
  add(zb, BTw1, nullptr, nullptr, 0, 0, y1, 896, 896, 4096, 896, 0);
  addT(BTf0, zb, nullptr, xT0, 896, 896, 1);
  addT(BTf1, zb, nullptr, xT1, 896, 896, 1);
  go();
  beg();  // F: adj = sigmoid(y @ z^T)
  add(y0, zb, nullptr, out + OFF_ADJ0, 4096, 4096, nullptr, 0, 896, 4096, 4096, 2);
  add(y1, zb, nullptr, out + OFF_ADJ1, 4096, 4096, nullptr, 0, 896, 4096, 4096, 2);
  go();

  // ---- feature decoders (0 || 1) -----------------------------------------
  beg();  // G: r = g @ t  [split-K]
  addS(g0b, xT0, partA, 4096, 896);
  addS(g1b, xT1, partB, 4096, 896);
  go();
  comb(nullptr, nullptr, 0, 0, u0, 896, 896, 0,
       nullptr, nullptr, 0, 0, u1, 896, 896, 0);
  beg();  // hrT: hr^T = tanh(Wd1^T @ r^T + bd1[row]) -> NT(A=BTd1, Bt=u)
  addT(BTd10, u0, pbd10, xT0, 896, 896, 1);
  addT(BTd11, u1, pbd11, xT1, 896, 1024, 1);
  go();
  beg();  // I: rin = g @ hr  [split-K]
  addS(g0b, xT0, partA, 4096, 896);
  addS(g1b, xT1, partB, 4096, 1024);
  go();
  comb(nullptr, nullptr, 0, 0, u0, 896, 896, 0,
       nullptr, nullptr, 0, 0, u1, 1024, 1024, 0);
  beg();  // J: rec = tanh(rin @ Wd2 + b)  (fp32 out)
  add(u0, BTd20, pbd20, out + OFF_REC0, 1024, 1024, nullptr, 0, 896, 4096, 1024, 1);
  add(u1, BTd21, pbd21, out + OFF_REC1, 1280, 1280, nullptr, 0, 1024, 4096, 1280, 1);
  go();

  // ---- q / p / cluster ---------------------------------------------------
  qkern<<<4096, 64, 0, stream>>>(out + OFF_Z, clus, out + OFF_Q);
  colsum_kern<<<5, 256, 0, stream>>>(out + OFF_Q, colsum);
  pkern<<<16, 256, 0, stream>>>(out + OFF_Q, colsum, out + OFF_P);
  hipMemcpyAsync(out + OFF_CL, (const void*)clus, 4095 * sizeof(float),
                 hipMemcpyDeviceToDevice, stream);
}